// Round 1
// baseline (2104.498 us; speedup 1.0000x reference)
//
#include <hip/hip_runtime.h>
#include <hip/hip_bf16.h>
#include <math.h>

#define HW 16384   // 128*128 bev pixels

__device__ __forceinline__ float gelu_exact(float x){
    return 0.5f * x * (1.0f + erff(x * 0.7071067811865475f));
}

// ---------------- feat transpose: (N,C,H,W) -> (N,H,W,C) ----------------
__global__ __launch_bounds__(256) void feat_transpose_k(
    const float* __restrict__ in, float* __restrict__ out, int Hl, int Wl, int total)
{
    int idx = blockIdx.x * 256 + threadIdx.x;
    if (idx >= total) return;
    int c   = idx & 127;
    int pix = idx >> 7;
    int x   = pix % Wl;
    int tt  = pix / Wl;
    int y   = tt % Hl;
    int n   = tt / Hl;
    out[idx] = in[((n * 128 + c) * Hl + y) * Wl + x];
}

// ---------------- conv3x3 (pad 1) + residual-add of input ----------------
// in: [128][128][128] CHW, w: OIHW (128,128,3,3), out = in + conv(in) + b
__global__ __launch_bounds__(256) void conv3x3_res_k(
    const float* __restrict__ in, const float* __restrict__ w,
    const float* __restrict__ b, float* __restrict__ out)
{
    int o = blockIdx.y;
    int x = threadIdx.x & 127;
    int y = (blockIdx.x << 1) + (threadIdx.x >> 7);
    float acc = b[o];
    const float* wbase = w + o * 128 * 9;
    for (int i = 0; i < 128; i++) {
        const float* ib = in + i * HW;
        const float* wi = wbase + i * 9;
        #pragma unroll
        for (int ky = 0; ky < 3; ky++) {
            int yy = y + ky - 1;
            if (yy < 0 || yy >= 128) continue;
            const float* row = ib + yy * 128;
            #pragma unroll
            for (int kx = 0; kx < 3; kx++) {
                int xx = x + kx - 1;
                if (xx >= 0 && xx < 128) acc += wi[ky * 3 + kx] * row[xx];
            }
        }
    }
    int pix = y * 128 + x;
    out[o * HW + pix] = acc + in[o * HW + pix];
}

// ---------------- instance norm (optionally a+b) over HW per channel ----------------
__global__ __launch_bounds__(256) void inorm_k(
    const float* __restrict__ a, const float* __restrict__ addc, float* __restrict__ out)
{
    int c = blockIdx.x;
    const float* pa = a + (size_t)c * HW;
    const float* pb = addc ? addc + (size_t)c * HW : nullptr;
    const bool hasb = (pb != nullptr);
    float s = 0.f, s2 = 0.f;
    for (int i = threadIdx.x; i < HW; i += 256) {
        float v = hasb ? (pa[i] + pb[i]) : pa[i];
        s += v; s2 += v * v;
    }
    #pragma unroll
    for (int off = 32; off > 0; off >>= 1) {
        s  += __shfl_down(s,  off);
        s2 += __shfl_down(s2, off);
    }
    __shared__ float ls[4], ls2[4], stats[2];
    int wid = threadIdx.x >> 6, lane = threadIdx.x & 63;
    if (lane == 0) { ls[wid] = s; ls2[wid] = s2; }
    __syncthreads();
    if (threadIdx.x == 0) {
        float t = 0.f, t2 = 0.f;
        for (int i = 0; i < 4; i++) { t += ls[i]; t2 += ls2[i]; }
        float mean = t * (1.0f / HW);
        float var  = t2 * (1.0f / HW) - mean * mean;
        stats[0] = mean;
        stats[1] = rsqrtf(var + 1e-5f);
    }
    __syncthreads();
    float mean = stats[0], rstd = stats[1];
    float* po = out + (size_t)c * HW;
    for (int i = threadIdx.x; i < HW; i += 256) {
        float v = hasb ? (pa[i] + pb[i]) : pa[i];
        po[i] = (v - mean) * rstd;
    }
}

// ---------------- offsets + sample-weights per pixel ----------------
// q0: CHW. Produces pts [pix][8][3], swn [pix][8][4], height -> d_out tail
__global__ __launch_bounds__(64) void offsw_k(
    const float* __restrict__ q0,
    const float* __restrict__ off_w, const float* __restrict__ off_b,
    const float* __restrict__ sw_w,  const float* __restrict__ sw_b,
    const float* __restrict__ bev_pos,
    float* __restrict__ pts, float* __restrict__ swn, float* __restrict__ height_out)
{
    int pix = blockIdx.x;
    int t = threadIdx.x;
    __shared__ float qv[128];
    __shared__ float raw[32];
    qv[t]      = q0[t * HW + pix];
    qv[t + 64] = q0[(t + 64) * HW + pix];
    __syncthreads();
    if (t < 24) {
        const float* wr = off_w + t * 128;
        float acc = off_b[t];
        for (int k = 0; k < 128; k++) acc += wr[k] * qv[k];
        float sv = 1.f / (1.f + expf(-acc));
        int p = t / 3, d = t - p * 3;
        float lim = (d == 2) ? (4.0f + 1e-6f) : (0.25f + 1e-6f);
        float offv = sv * 2.f * lim - lim;
        const float pcmin[3] = {-50.f, -50.f, -4.f};
        const float rng[3]   = {100.f, 100.f, 8.f};
        float refv = bev_pos[pix * 3 + d] * rng[d] + pcmin[d];
        pts[(pix * 8 + p) * 3 + d] = refv + offv;
        if (d == 2) height_out[p * HW + pix] = offv;
    } else if (t < 56) {
        int r = t - 24;
        const float* wr = sw_w + r * 128;
        float acc = sw_b[r];
        for (int k = 0; k < 128; k++) acc += wr[k] * qv[k];
        raw[r] = acc;
    }
    __syncthreads();
    if (t < 8) {
        float m = raw[t * 4];
        #pragma unroll
        for (int l = 1; l < 4; l++) m = fmaxf(m, raw[t * 4 + l]);
        float e[4], sum = 0.f;
        #pragma unroll
        for (int l = 0; l < 4; l++) { e[l] = expf(raw[t * 4 + l] - m); sum += e[l]; }
        float inv = 1.f / sum;
        #pragma unroll
        for (int l = 0; l < 4; l++) swn[(pix * 8 + t) * 4 + l] = e[l] * inv;
    }
}

// ---------------- fused multi-cam/level bilinear sampling + PE MLP ----------------
// one block per pixel, 128 threads = channel dim; loops p=0..7 internally.
// sf out layout: [pix][p*128+c]
__global__ __launch_bounds__(128) void sample_pe_k(
    const float* __restrict__ featT, const float* __restrict__ pts,
    const float* __restrict__ swn,   const float* __restrict__ l2i,
    const float* __restrict__ pe_w1, const float* __restrict__ pe_b1,
    const float* __restrict__ pe_w2, const float* __restrict__ pe_b2,
    float* __restrict__ sf)
{
    int pix = blockIdx.x;
    int t = threadIdx.x;
    __shared__ float pts_s[24];
    __shared__ float swl_s[32];
    __shared__ float M[96];
    __shared__ float hsT[256][8];
    if (t < 96) M[t] = l2i[t];
    if (t < 24) pts_s[t] = pts[pix * 24 + t];
    if (t < 32) swl_s[t] = swn[pix * 32 + t];
    // PE layer-1 weights for this thread's two hidden units (j = t, j = 128+t)
    float w10 = pe_w1[t],        w11 = pe_w1[256 + t],  w12 = pe_w1[512 + t];
    float w20 = pe_w1[128 + t],  w21 = pe_w1[384 + t],  w22 = pe_w1[640 + t];
    float b1a = pe_b1[t], b1b = pe_b1[128 + t];
    float bias2 = pe_b2[t];
    __syncthreads();

    float acc[8];
    #pragma unroll
    for (int p = 0; p < 8; p++) {
        float rn0 = (pts_s[p * 3 + 0] + 50.f) * 0.01f;
        float rn1 = (pts_s[p * 3 + 1] + 50.f) * 0.01f;
        float rn2 = (pts_s[p * 3 + 2] + 4.f) * 0.125f;
        hsT[t][p]       = fmaxf(b1a + rn0 * w10 + rn1 * w11 + rn2 * w12, 0.f);
        hsT[128 + t][p] = fmaxf(b1b + rn0 * w20 + rn1 * w21 + rn2 * w22, 0.f);
        acc[p] = bias2;
    }
    __syncthreads();
    // PE layer-2: acc[p] += sum_k h[p][k] * w2[k][c]
    #pragma unroll 4
    for (int k = 0; k < 256; k++) {
        float wv = pe_w2[k * 128 + t];
        const float4* hp = (const float4*)&hsT[k][0];
        float4 h0 = hp[0], h1 = hp[1];
        acc[0] += h0.x * wv; acc[1] += h0.y * wv; acc[2] += h0.z * wv; acc[3] += h0.w * wv;
        acc[4] += h1.x * wv; acc[5] += h1.y * wv; acc[6] += h1.z * wv; acc[7] += h1.w * wv;
    }

    const int lHt[4] = {32, 16, 8, 4}, lWt[4] = {88, 44, 22, 11};
    const int loff[4] = {0, 2162688, 2703360, 2838528};
    #pragma unroll 1
    for (int p = 0; p < 8; p++) {
        float X = pts_s[p * 3], Y = pts_s[p * 3 + 1], Z = pts_s[p * 3 + 2];
        float a = acc[p];
        #pragma unroll 1
        for (int n = 0; n < 6; n++) {
            const float* Mn = &M[n * 16];
            float zc = Mn[8] * X + Mn[9] * Y + Mn[10] * Z + Mn[11];
            if (zc > 1e-5f) {
                float inv = 1.f / zc;
                float xn = (Mn[0] * X + Mn[1] * Y + Mn[2] * Z + Mn[3]) * inv * (1.f / 704.f);
                float yn = (Mn[4] * X + Mn[5] * Y + Mn[6] * Z + Mn[7]) * inv * (1.f / 256.f);
                #pragma unroll
                for (int l = 0; l < 4; l++) {
                    int Wl = lWt[l], Hl = lHt[l];
                    float wl = swl_s[p * 4 + l];
                    float px = xn * Wl - 0.5f, py = yn * Hl - 0.5f;
                    px = fminf(fmaxf(px, -1e4f), 1e4f);
                    py = fminf(fmaxf(py, -1e4f), 1e4f);
                    float x0f = floorf(px), y0f = floorf(py);
                    float wx = px - x0f, wy = py - y0f;
                    int x0 = (int)x0f, y0 = (int)y0f;
                    const float* base = featT + loff[l] + n * Hl * Wl * 128 + t;
                    bool xi0 = (unsigned)x0 < (unsigned)Wl, xi1 = (unsigned)(x0 + 1) < (unsigned)Wl;
                    bool yi0 = (unsigned)y0 < (unsigned)Hl, yi1 = (unsigned)(y0 + 1) < (unsigned)Hl;
                    if (xi0 && yi0) a += wl * (1.f - wx) * (1.f - wy) * base[(y0 * Wl + x0) * 128];
                    if (xi1 && yi0) a += wl * wx * (1.f - wy)        * base[(y0 * Wl + x0 + 1) * 128];
                    if (xi0 && yi1) a += wl * (1.f - wx) * wy        * base[((y0 + 1) * Wl + x0) * 128];
                    if (xi1 && yi1) a += wl * wx * wy                * base[((y0 + 1) * Wl + x0 + 1) * 128];
                }
            }
        }
        sf[pix * 1024 + p * 128 + t] = a;
    }
}

// ---------------- generic fp32 GEMM: out[n][m] = act(bias[m] + sum_k X[n][k]*W[m][k]) ----------------
// ACT: 0 none, 1 gelu.  TRANS_OUT: store out[m][n] (ld = N) instead.
template<int ACT, int TRANS_OUT>
__global__ __launch_bounds__(256) void gemm_k(
    const float* __restrict__ X, const float* __restrict__ W,
    const float* __restrict__ bias, float* __restrict__ out,
    int N, int K, int M)
{
    __shared__ float Xs[16][68];
    __shared__ float Ws[16][68];
    int t = threadIdx.x;
    int nb = blockIdx.y * 64, mb = blockIdx.x * 64;
    int tn = (t & 15) * 4;  // n offset in tile
    int tm = (t >> 4) * 4;  // m offset in tile
    int lr = t >> 2;        // load row 0..63
    int lk = (t & 3) * 4;   // load k offset
    float acc[4][4] = {};
    for (int kb = 0; kb < K; kb += 16) {
        float4 xv = *(const float4*)&X[(size_t)(nb + lr) * K + kb + lk];
        float4 wv = *(const float4*)&W[(size_t)(mb + lr) * K + kb + lk];
        Xs[lk + 0][lr] = xv.x; Xs[lk + 1][lr] = xv.y; Xs[lk + 2][lr] = xv.z; Xs[lk + 3][lr] = xv.w;
        Ws[lk + 0][lr] = wv.x; Ws[lk + 1][lr] = wv.y; Ws[lk + 2][lr] = wv.z; Ws[lk + 3][lr] = wv.w;
        __syncthreads();
        #pragma unroll
        for (int k = 0; k < 16; k++) {
            float4 xa = *(const float4*)&Xs[k][tn];
            float4 wb = *(const float4*)&Ws[k][tm];
            acc[0][0] += xa.x * wb.x; acc[0][1] += xa.x * wb.y; acc[0][2] += xa.x * wb.z; acc[0][3] += xa.x * wb.w;
            acc[1][0] += xa.y * wb.x; acc[1][1] += xa.y * wb.y; acc[1][2] += xa.y * wb.z; acc[1][3] += xa.y * wb.w;
            acc[2][0] += xa.z * wb.x; acc[2][1] += xa.z * wb.y; acc[2][2] += xa.z * wb.z; acc[2][3] += xa.z * wb.w;
            acc[3][0] += xa.w * wb.x; acc[3][1] += xa.w * wb.y; acc[3][2] += xa.w * wb.z; acc[3][3] += xa.w * wb.w;
        }
        __syncthreads();
    }
    if (!TRANS_OUT) {
        #pragma unroll
        for (int i = 0; i < 4; i++) {
            float4 v;
            float* pv = (float*)&v;
            #pragma unroll
            for (int j = 0; j < 4; j++) {
                float val = acc[i][j] + bias[mb + tm + j];
                if (ACT == 1) val = gelu_exact(val);
                pv[j] = val;
            }
            *(float4*)&out[(size_t)(nb + tn + i) * M + mb + tm] = v;
        }
    } else {
        #pragma unroll
        for (int j = 0; j < 4; j++) {
            float bj = bias[mb + tm + j];
            float4 v;
            float* pv = (float*)&v;
            #pragma unroll
            for (int i = 0; i < 4; i++) {
                float val = acc[i][j] + bj;
                if (ACT == 1) val = gelu_exact(val);
                pv[i] = val;
            }
            *(float4*)&out[(size_t)(mb + tm + j) * N + nb + tn] = v;
        }
    }
}

extern "C" void kernel_launch(void* const* d_in, const int* in_sizes, int n_in,
                              void* d_out, int out_size, void* d_ws, size_t ws_size,
                              hipStream_t stream)
{
    const float* feat[4] = {(const float*)d_in[0], (const float*)d_in[1],
                            (const float*)d_in[2], (const float*)d_in[3]};
    const float* l2i       = (const float*)d_in[4];
    const float* bev_query = (const float*)d_in[5];
    const float* bev_pos   = (const float*)d_in[6];
    const float* in_w  = (const float*)d_in[7];  const float* in_b  = (const float*)d_in[8];
    const float* off_w = (const float*)d_in[9];  const float* off_b = (const float*)d_in[10];
    const float* sw_w  = (const float*)d_in[11]; const float* sw_b  = (const float*)d_in[12];
    const float* pe_w1 = (const float*)d_in[13]; const float* pe_b1 = (const float*)d_in[14];
    const float* pe_w2 = (const float*)d_in[15]; const float* pe_b2 = (const float*)d_in[16];
    const float* mid_w1 = (const float*)d_in[17]; const float* mid_b1 = (const float*)d_in[18];
    const float* mid_w2 = (const float*)d_in[19]; const float* mid_b2 = (const float*)d_in[20];
    const float* mid_w3 = (const float*)d_in[21]; const float* mid_b3 = (const float*)d_in[22];
    const float* out_w  = (const float*)d_in[23]; const float* out_b  = (const float*)d_in[24];

    float* ws = (float*)d_ws;
    // workspace layout (floats), total 33,149,952 fl = 132.6 MB
    float* fT = ws;               // 2,872,320 : transposed feats (NHWC per level)
    float* Bb = ws + 2872320;     // 2,097,152 : conv1 out; later m3 (CHW)
    float* Cb = Bb + 2097152;     // 2,097,152 : q0; later conv2 out
    float* Dp = Cb + 2097152;     //   393,216 : pts [pix][8][3]
    float* Eb = Dp + 393216;      //   524,288 : swn [pix][8][4]
    float* Fb = Eb + 524288;      // 16,777,216 : sf [pix][1024]; later m2 [pix][512]
    float* Gb = Fb + 16777216;    // 8,388,608 : m1 [pix][512]; later q1 (CHW)
    float* q_out = (float*)d_out;
    float* h_out = q_out + 2097152;

    const int lH[4] = {32, 16, 8, 4}, lW[4] = {88, 44, 22, 11};
    const int loff[4] = {0, 2162688, 2703360, 2838528};
    for (int l = 0; l < 4; l++) {
        int total = 6 * lH[l] * lW[l] * 128;
        feat_transpose_k<<<(total + 255) / 256, 256, 0, stream>>>(feat[l], fT + loff[l], lH[l], lW[l], total);
    }
    // q0 = inorm(bev_query + conv3x3(bev_query))
    conv3x3_res_k<<<dim3(64, 128), 256, 0, stream>>>(bev_query, in_w, in_b, Bb);
    inorm_k<<<128, 256, 0, stream>>>(Bb, nullptr, Cb);
    // offsets, sample weights, pts, height
    offsw_k<<<16384, 64, 0, stream>>>(Cb, off_w, off_b, sw_w, sw_b, bev_pos, Dp, Eb, h_out);
    // sampling + PE  -> sf [pix][1024]
    sample_pe_k<<<16384, 128, 0, stream>>>(fT, Dp, Eb, l2i, pe_w1, pe_b1, pe_w2, pe_b2, Fb);
    // mid MLP: 1024 -> 512 (gelu) -> 512 (gelu) -> 128 (linear, stored CHW)
    gemm_k<1, 0><<<dim3(8, 256), 256, 0, stream>>>(Fb, mid_w1, mid_b1, Gb, 16384, 1024, 512);
    gemm_k<1, 0><<<dim3(8, 256), 256, 0, stream>>>(Gb, mid_w2, mid_b2, Fb, 16384, 512, 512);
    gemm_k<0, 1><<<dim3(2, 256), 256, 0, stream>>>(Fb, mid_w3, mid_b3, Bb, 16384, 512, 128);
    // q1 = inorm(q0 + m)
    inorm_k<<<128, 256, 0, stream>>>(Cb, Bb, Gb);
    // q = inorm(q1 + conv3x3(q1))
    conv3x3_res_k<<<dim3(64, 128), 256, 0, stream>>>(Gb, out_w, out_b, Cb);
    inorm_k<<<128, 256, 0, stream>>>(Cb, nullptr, q_out);
}

// Round 2
// 919.040 us; speedup vs baseline: 2.2899x; 2.2899x over previous
//
#include <hip/hip_runtime.h>
#include <hip/hip_bf16.h>
#include <math.h>

#define HW 16384   // 128*128 bev pixels

typedef __attribute__((ext_vector_type(8))) short short8;
typedef __attribute__((ext_vector_type(4))) float floatx4;

__device__ __forceinline__ float gelu_exact(float x){
    return 0.5f * x * (1.0f + erff(x * 0.7071067811865475f));
}

// ---------------- feat transpose: (N,C,H,W) -> (N,H,W,C) ----------------
__global__ __launch_bounds__(256) void feat_transpose_k(
    const float* __restrict__ in, float* __restrict__ out, int Hl, int Wl, int total)
{
    int idx = blockIdx.x * 256 + threadIdx.x;
    if (idx >= total) return;
    int c   = idx & 127;
    int pix = idx >> 7;
    int x   = pix % Wl;
    int tt  = pix / Wl;
    int y   = tt % Hl;
    int n   = tt / Hl;
    out[idx] = in[((n * 128 + c) * Hl + y) * Wl + x];
}

// ---------------- fp32 -> bf16 conversion ----------------
__global__ __launch_bounds__(256) void cvt_bf16_k(
    const float* __restrict__ in, __hip_bfloat16* __restrict__ out, int n)
{
    int i = blockIdx.x * 256 + threadIdx.x;
    if (i < n) out[i] = __float2bfloat16(in[i]);
}

// ---------------- conv weight rearrange: w[o][i][dy][dx] -> wre[o][(dy*3+dx)*128+i] bf16 ----------------
__global__ __launch_bounds__(256) void convw_k(
    const float* __restrict__ w, __hip_bfloat16* __restrict__ wre)
{
    int o = blockIdx.x;
    for (int idx = threadIdx.x; idx < 1152; idx += 256) {
        int s = idx >> 7, i = idx & 127;
        wre[o * 1152 + idx] = __float2bfloat16(w[(o * 128 + i) * 9 + s]);
    }
}

// ---------------- im2col (shift-major K): A[pix][s*128+c] bf16 ----------------
// input q: fp32 CHW [128][128][128]
__global__ __launch_bounds__(256) void im2col_k(
    const float* __restrict__ q, __hip_bfloat16* __restrict__ A)
{
    __shared__ __hip_bfloat16 win[128][3][68];
    int b = blockIdx.x;           // 256 blocks: half-row each
    int y = b >> 1, xb = (b & 1) * 64;
    int t = threadIdx.x;
    int xi = t & 63, cg = t >> 6;
    for (int c = cg; c < 128; c += 4) {
        const float* qc = q + c * HW;
        #pragma unroll
        for (int dy = 0; dy < 3; dy++) {
            int gy = y + dy - 1;
            bool yok = ((unsigned)gy < 128u);
            int gx = xb - 1 + xi;
            float v = (yok && (unsigned)gx < 128u) ? qc[gy * 128 + gx] : 0.f;
            win[c][dy][xi] = __float2bfloat16(v);
            if (xi < 2) {
                int gx2 = xb - 1 + 64 + xi;
                float v2 = (yok && (unsigned)gx2 < 128u) ? qc[gy * 128 + gx2] : 0.f;
                win[c][dy][64 + xi] = __float2bfloat16(v2);
            }
        }
    }
    __syncthreads();
    int p = t >> 2, c0 = (t & 3) * 32;
    size_t pix = (size_t)(y * 128 + xb + p);
    #pragma unroll 1
    for (int s = 0; s < 9; s++) {
        int dy = s / 3, dx = s - dy * 3;
        int wx = p + dx;  // 0..65
        #pragma unroll
        for (int g = 0; g < 4; g++) {
            int c = c0 + g * 8;
            union { __hip_bfloat16 h[8]; uint4 u; } pk;
            #pragma unroll
            for (int j = 0; j < 8; j++) pk.h[j] = win[c + j][dy][wx];
            *(uint4*)&A[pix * 1152 + s * 128 + c] = pk.u;
        }
    }
}

// ---------------- bf16 MFMA GEMM: out[m][n] = act(bias[n] + sum_k X[m][k] W[n][k]) ----------------
// BN = 128 fixed. OUTT: 0 -> bf16 [M][N] row-major; 1 -> fp32 [N][M] transposed (CHW)
template<int BM, int ACT, int OUTT>
__global__ __launch_bounds__(256) void bgemm_k(
    const __hip_bfloat16* __restrict__ X, const __hip_bfloat16* __restrict__ W,
    const float* __restrict__ bias, void* __restrict__ outp,
    int M, int K, int N)
{
    constexpr int ROWS = BM + 128;
    __shared__ __align__(16) __hip_bfloat16 SH[ROWS * 32];
    __hip_bfloat16* As = SH;
    __hip_bfloat16* Bs = SH + BM * 32;
    int t = threadIdx.x;
    int w = t >> 6, lane = t & 63;
    int mb = blockIdx.y * BM, nb = blockIdx.x * 128;
    constexpr int WM = BM / 2;
    constexpr int MI = WM / 16;
    int wm = (w & 1) * WM, wn = (w >> 1) * 64;
    int lm = lane & 15, lq = lane >> 4;
    floatx4 zero = {0.f, 0.f, 0.f, 0.f};
    floatx4 acc[MI][4];
    #pragma unroll
    for (int i = 0; i < MI; i++)
        #pragma unroll
        for (int j = 0; j < 4; j++) acc[i][j] = zero;
    constexpr int ITERS = (ROWS * 4) / 256;  // 16B chunks per thread per k-step
    for (int kb = 0; kb < K; kb += 32) {
        __syncthreads();
        #pragma unroll
        for (int it = 0; it < ITERS; it++) {
            int chunk = it * 256 + t;
            int row = chunk >> 2, ko = (chunk & 3) * 8;
            const __hip_bfloat16* src = (row < BM)
                ? (X + (size_t)(mb + row) * K + kb + ko)
                : (W + (size_t)(nb + row - BM) * K + kb + ko);
            *(uint4*)&SH[chunk * 8] = *(const uint4*)src;
        }
        __syncthreads();
        short8 af[MI], bf[4];
        #pragma unroll
        for (int i = 0; i < MI; i++)
            af[i] = *(const short8*)&As[(wm + i * 16 + lm) * 32 + lq * 8];
        #pragma unroll
        for (int j = 0; j < 4; j++)
            bf[j] = *(const short8*)&Bs[(wn + j * 16 + lm) * 32 + lq * 8];
        #pragma unroll
        for (int i = 0; i < MI; i++)
            #pragma unroll
            for (int j = 0; j < 4; j++)
                acc[i][j] = __builtin_amdgcn_mfma_f32_16x16x32_bf16(af[i], bf[j], acc[i][j], 0, 0, 0);
    }
    #pragma unroll
    for (int i = 0; i < MI; i++) {
        #pragma unroll
        for (int j = 0; j < 4; j++) {
            int n = nb + wn + j * 16 + lm;
            float bv = bias[n];
            #pragma unroll
            for (int r = 0; r < 4; r++) {
                int m = mb + wm + i * 16 + lq * 4 + r;
                float v = acc[i][j][r] + bv;
                if (ACT) v = gelu_exact(v);
                if (OUTT == 0) ((__hip_bfloat16*)outp)[(size_t)m * N + n] = __float2bfloat16(v);
                else           ((float*)outp)[(size_t)n * M + m] = v;
            }
        }
    }
}

// ---------------- instance norm (optionally a+b) over HW per channel ----------------
__global__ __launch_bounds__(256) void inorm_k(
    const float* __restrict__ a, const float* __restrict__ addc, float* __restrict__ out)
{
    int c = blockIdx.x;
    const float* pa = a + (size_t)c * HW;
    const float* pb = addc ? addc + (size_t)c * HW : nullptr;
    const bool hasb = (pb != nullptr);
    float s = 0.f, s2 = 0.f;
    for (int i = threadIdx.x; i < HW; i += 256) {
        float v = hasb ? (pa[i] + pb[i]) : pa[i];
        s += v; s2 += v * v;
    }
    #pragma unroll
    for (int off = 32; off > 0; off >>= 1) {
        s  += __shfl_down(s,  off);
        s2 += __shfl_down(s2, off);
    }
    __shared__ float ls[4], ls2[4], stats[2];
    int wid = threadIdx.x >> 6, lane = threadIdx.x & 63;
    if (lane == 0) { ls[wid] = s; ls2[wid] = s2; }
    __syncthreads();
    if (threadIdx.x == 0) {
        float t = 0.f, t2 = 0.f;
        for (int i = 0; i < 4; i++) { t += ls[i]; t2 += ls2[i]; }
        float mean = t * (1.0f / HW);
        float var  = t2 * (1.0f / HW) - mean * mean;
        stats[0] = mean;
        stats[1] = rsqrtf(var + 1e-5f);
    }
    __syncthreads();
    float mean = stats[0], rstd = stats[1];
    float* po = out + (size_t)c * HW;
    for (int i = threadIdx.x; i < HW; i += 256) {
        float v = hasb ? (pa[i] + pb[i]) : pa[i];
        po[i] = (v - mean) * rstd;
    }
}

// ---------------- offsets + sample-weights per pixel ----------------
__global__ __launch_bounds__(64) void offsw_k(
    const float* __restrict__ q0,
    const float* __restrict__ off_w, const float* __restrict__ off_b,
    const float* __restrict__ sw_w,  const float* __restrict__ sw_b,
    const float* __restrict__ bev_pos,
    float* __restrict__ pts, float* __restrict__ swn, float* __restrict__ height_out)
{
    int pix = blockIdx.x;
    int t = threadIdx.x;
    __shared__ float qv[128];
    __shared__ float raw[32];
    qv[t]      = q0[t * HW + pix];
    qv[t + 64] = q0[(t + 64) * HW + pix];
    __syncthreads();
    if (t < 24) {
        const float* wr = off_w + t * 128;
        float acc = off_b[t];
        for (int k = 0; k < 128; k++) acc += wr[k] * qv[k];
        float sv = 1.f / (1.f + expf(-acc));
        int p = t / 3, d = t - p * 3;
        float lim = (d == 2) ? (4.0f + 1e-6f) : (0.25f + 1e-6f);
        float offv = sv * 2.f * lim - lim;
        const float pcmin[3] = {-50.f, -50.f, -4.f};
        const float rng[3]   = {100.f, 100.f, 8.f};
        float refv = bev_pos[pix * 3 + d] * rng[d] + pcmin[d];
        pts[(pix * 8 + p) * 3 + d] = refv + offv;
        if (d == 2) height_out[p * HW + pix] = offv;
    } else if (t < 56) {
        int r = t - 24;
        const float* wr = sw_w + r * 128;
        float acc = sw_b[r];
        for (int k = 0; k < 128; k++) acc += wr[k] * qv[k];
        raw[r] = acc;
    }
    __syncthreads();
    if (t < 8) {
        float m = raw[t * 4];
        #pragma unroll
        for (int l = 1; l < 4; l++) m = fmaxf(m, raw[t * 4 + l]);
        float e[4], sum = 0.f;
        #pragma unroll
        for (int l = 0; l < 4; l++) { e[l] = expf(raw[t * 4 + l] - m); sum += e[l]; }
        float inv = 1.f / sum;
        #pragma unroll
        for (int l = 0; l < 4; l++) swn[(pix * 8 + t) * 4 + l] = e[l] * inv;
    }
}

// ---------------- fused sampling + PE MLP -> sf bf16 [pix][p*128+c] ----------------
__global__ __launch_bounds__(128) void sample_pe_k(
    const float* __restrict__ featT, const float* __restrict__ pts,
    const float* __restrict__ swn,   const float* __restrict__ l2i,
    const float* __restrict__ pe_w1, const float* __restrict__ pe_b1,
    const float* __restrict__ pe_w2, const float* __restrict__ pe_b2,
    __hip_bfloat16* __restrict__ sf)
{
    int pix = blockIdx.x;
    int t = threadIdx.x;
    __shared__ float pts_s[24];
    __shared__ float swl_s[32];
    __shared__ float M[96];
    __shared__ float hsT[256][8];
    if (t < 96) M[t] = l2i[t];
    if (t < 24) pts_s[t] = pts[pix * 24 + t];
    if (t < 32) swl_s[t] = swn[pix * 32 + t];
    float w10 = pe_w1[t],        w11 = pe_w1[256 + t],  w12 = pe_w1[512 + t];
    float w20 = pe_w1[128 + t],  w21 = pe_w1[384 + t],  w22 = pe_w1[640 + t];
    float b1a = pe_b1[t], b1b = pe_b1[128 + t];
    float bias2 = pe_b2[t];
    __syncthreads();

    float acc[8];
    #pragma unroll
    for (int p = 0; p < 8; p++) {
        float rn0 = (pts_s[p * 3 + 0] + 50.f) * 0.01f;
        float rn1 = (pts_s[p * 3 + 1] + 50.f) * 0.01f;
        float rn2 = (pts_s[p * 3 + 2] + 4.f) * 0.125f;
        hsT[t][p]       = fmaxf(b1a + rn0 * w10 + rn1 * w11 + rn2 * w12, 0.f);
        hsT[128 + t][p] = fmaxf(b1b + rn0 * w20 + rn1 * w21 + rn2 * w22, 0.f);
        acc[p] = bias2;
    }
    __syncthreads();
    #pragma unroll 4
    for (int k = 0; k < 256; k++) {
        float wv = pe_w2[k * 128 + t];
        const float4* hp = (const float4*)&hsT[k][0];
        float4 h0 = hp[0], h1 = hp[1];
        acc[0] += h0.x * wv; acc[1] += h0.y * wv; acc[2] += h0.z * wv; acc[3] += h0.w * wv;
        acc[4] += h1.x * wv; acc[5] += h1.y * wv; acc[6] += h1.z * wv; acc[7] += h1.w * wv;
    }

    const int lHt[4] = {32, 16, 8, 4}, lWt[4] = {88, 44, 22, 11};
    const int loff[4] = {0, 2162688, 2703360, 2838528};
    #pragma unroll 1
    for (int p = 0; p < 8; p++) {
        float X = pts_s[p * 3], Y = pts_s[p * 3 + 1], Z = pts_s[p * 3 + 2];
        float a = acc[p];
        #pragma unroll 1
        for (int n = 0; n < 6; n++) {
            const float* Mn = &M[n * 16];
            float zc = Mn[8] * X + Mn[9] * Y + Mn[10] * Z + Mn[11];
            if (zc > 1e-5f) {
                float inv = 1.f / zc;
                float xn = (Mn[0] * X + Mn[1] * Y + Mn[2] * Z + Mn[3]) * inv * (1.f / 704.f);
                float yn = (Mn[4] * X + Mn[5] * Y + Mn[6] * Z + Mn[7]) * inv * (1.f / 256.f);
                #pragma unroll
                for (int l = 0; l < 4; l++) {
                    int Wl = lWt[l], Hl = lHt[l];
                    float wl = swl_s[p * 4 + l];
                    float px = xn * Wl - 0.5f, py = yn * Hl - 0.5f;
                    px = fminf(fmaxf(px, -1e4f), 1e4f);
                    py = fminf(fmaxf(py, -1e4f), 1e4f);
                    float x0f = floorf(px), y0f = floorf(py);
                    float wx = px - x0f, wy = py - y0f;
                    int x0 = (int)x0f, y0 = (int)y0f;
                    const float* base = featT + loff[l] + n * Hl * Wl * 128 + t;
                    bool xi0 = (unsigned)x0 < (unsigned)Wl, xi1 = (unsigned)(x0 + 1) < (unsigned)Wl;
                    bool yi0 = (unsigned)y0 < (unsigned)Hl, yi1 = (unsigned)(y0 + 1) < (unsigned)Hl;
                    if (xi0 && yi0) a += wl * (1.f - wx) * (1.f - wy) * base[(y0 * Wl + x0) * 128];
                    if (xi1 && yi0) a += wl * wx * (1.f - wy)        * base[(y0 * Wl + x0 + 1) * 128];
                    if (xi0 && yi1) a += wl * (1.f - wx) * wy        * base[((y0 + 1) * Wl + x0) * 128];
                    if (xi1 && yi1) a += wl * wx * wy                * base[((y0 + 1) * Wl + x0 + 1) * 128];
                }
            }
        }
        sf[(size_t)pix * 1024 + p * 128 + t] = __float2bfloat16(a);
    }
}

extern "C" void kernel_launch(void* const* d_in, const int* in_sizes, int n_in,
                              void* d_out, int out_size, void* d_ws, size_t ws_size,
                              hipStream_t stream)
{
    const float* feat[4] = {(const float*)d_in[0], (const float*)d_in[1],
                            (const float*)d_in[2], (const float*)d_in[3]};
    const float* l2i       = (const float*)d_in[4];
    const float* bev_query = (const float*)d_in[5];
    const float* bev_pos   = (const float*)d_in[6];
    const float* in_w  = (const float*)d_in[7];  const float* in_b  = (const float*)d_in[8];
    const float* off_w = (const float*)d_in[9];  const float* off_b = (const float*)d_in[10];
    const float* sw_w  = (const float*)d_in[11]; const float* sw_b  = (const float*)d_in[12];
    const float* pe_w1 = (const float*)d_in[13]; const float* pe_b1 = (const float*)d_in[14];
    const float* pe_w2 = (const float*)d_in[15]; const float* pe_b2 = (const float*)d_in[16];
    const float* mid_w1 = (const float*)d_in[17]; const float* mid_b1 = (const float*)d_in[18];
    const float* mid_w2 = (const float*)d_in[19]; const float* mid_b2 = (const float*)d_in[20];
    const float* mid_w3 = (const float*)d_in[21]; const float* mid_b3 = (const float*)d_in[22];
    const float* out_w  = (const float*)d_in[23]; const float* out_b  = (const float*)d_in[24];

    float* ws = (float*)d_ws;
    // workspace layout (floats), total 28,406,784 fl = 113.6 MB
    float* fT  = ws;                    // 2,872,320 : transposed feats
    float* Bb  = ws + 2872320;          // 2,097,152 : conv out / m3 (CHW)
    float* Cb  = Bb + 2097152;          // 2,097,152 : q0 / conv2 out
    float* Gb  = Cb + 2097152;          // 2,097,152 : q1 (CHW)
    float* Dp  = Gb + 2097152;          //   393,216 : pts
    float* Eb  = Dp + 393216;           //   524,288 : swn
    float* Af  = Eb + 524288;           // 9,437,184 : im2col A bf16 (aliases sfb)
    __hip_bfloat16* Aim = (__hip_bfloat16*)Af;
    __hip_bfloat16* sfb = (__hip_bfloat16*)Af;      // 16,777,216 bf16 (disjoint lifetime)
    float* M1f = Af + 9437184;          // 4,194,304 : m1 bf16
    __hip_bfloat16* m1b = (__hip_bfloat16*)M1f;
    float* M2f = M1f + 4194304;         // 4,194,304 : m2 bf16
    __hip_bfloat16* m2b = (__hip_bfloat16*)M2f;
    float* Wc  = M2f + 4194304;         //    73,728 : conv weights bf16 (reused conv1/conv2)
    __hip_bfloat16* Wcv = (__hip_bfloat16*)Wc;
    float* W1f = Wc + 73728;            //   262,144
    __hip_bfloat16* Wb1 = (__hip_bfloat16*)W1f;
    float* W2f = W1f + 262144;          //   131,072
    __hip_bfloat16* Wb2 = (__hip_bfloat16*)W2f;
    float* W3f = W2f + 131072;          //    32,768
    __hip_bfloat16* Wb3 = (__hip_bfloat16*)W3f;

    float* q_out = (float*)d_out;
    float* h_out = q_out + 2097152;

    const int lH[4] = {32, 16, 8, 4}, lW[4] = {88, 44, 22, 11};
    const int loff[4] = {0, 2162688, 2703360, 2838528};
    for (int l = 0; l < 4; l++) {
        int total = 6 * lH[l] * lW[l] * 128;
        feat_transpose_k<<<(total + 255) / 256, 256, 0, stream>>>(feat[l], fT + loff[l], lH[l], lW[l], total);
    }
    // weight prep
    cvt_bf16_k<<<(524288 + 255) / 256, 256, 0, stream>>>(mid_w1, Wb1, 524288);
    cvt_bf16_k<<<(262144 + 255) / 256, 256, 0, stream>>>(mid_w2, Wb2, 262144);
    cvt_bf16_k<<<(65536  + 255) / 256, 256, 0, stream>>>(mid_w3, Wb3, 65536);

    // conv1: q0 = inorm(bev_query + conv3x3(bev_query))
    convw_k<<<128, 256, 0, stream>>>(in_w, Wcv);
    im2col_k<<<256, 256, 0, stream>>>(bev_query, Aim);
    bgemm_k<64, 0, 1><<<dim3(1, 256), 256, 0, stream>>>(Aim, Wcv, in_b, Bb, HW, 1152, 128);
    inorm_k<<<128, 256, 0, stream>>>(Bb, bev_query, Cb);

    // offsets, sample weights, pts, height
    offsw_k<<<HW, 64, 0, stream>>>(Cb, off_w, off_b, sw_w, sw_b, bev_pos, Dp, Eb, h_out);
    // sampling + PE  -> sf bf16 [pix][1024]
    sample_pe_k<<<HW, 128, 0, stream>>>(fT, Dp, Eb, l2i, pe_w1, pe_b1, pe_w2, pe_b2, sfb);

    // mid MLP (bf16 MFMA): 1024 -> 512 gelu -> 512 gelu -> 128 linear (CHW fp32)
    bgemm_k<128, 1, 0><<<dim3(4, 128), 256, 0, stream>>>(sfb, Wb1, mid_b1, m1b, HW, 1024, 512);
    bgemm_k<128, 1, 0><<<dim3(4, 128), 256, 0, stream>>>(m1b, Wb2, mid_b2, m2b, HW, 512, 512);
    bgemm_k<64, 0, 1><<<dim3(1, 256), 256, 0, stream>>>(m2b, Wb3, mid_b3, Bb, HW, 512, 128);

    // q1 = inorm(q0 + m)
    inorm_k<<<128, 256, 0, stream>>>(Cb, Bb, Gb);

    // conv2: q = inorm(q1 + conv3x3(q1))
    convw_k<<<128, 256, 0, stream>>>(out_w, Wcv);
    im2col_k<<<256, 256, 0, stream>>>(Gb, Aim);
    bgemm_k<64, 0, 1><<<dim3(1, 256), 256, 0, stream>>>(Aim, Wcv, out_b, Cb, HW, 1152, 128);
    inorm_k<<<128, 256, 0, stream>>>(Cb, Gb, q_out);
}

// Round 4
// 705.554 us; speedup vs baseline: 2.9828x; 1.3026x over previous
//
#include <hip/hip_runtime.h>
#include <hip/hip_bf16.h>
#include <math.h>

#define HW 16384   // 128*128 bev pixels

typedef __attribute__((ext_vector_type(8))) short short8;
typedef __attribute__((ext_vector_type(4))) float floatx4;

__device__ __forceinline__ float gelu_exact(float x){
    return 0.5f * x * (1.0f + erff(x * 0.7071067811865475f));
}

// ---------------- feat transpose: (N,C,H,W) -> (N,H,W,C) ----------------
__global__ __launch_bounds__(256) void feat_transpose_k(
    const float* __restrict__ in, float* __restrict__ out, int Hl, int Wl, int total)
{
    int idx = blockIdx.x * 256 + threadIdx.x;
    if (idx >= total) return;
    int c   = idx & 127;
    int pix = idx >> 7;
    int x   = pix % Wl;
    int tt  = pix / Wl;
    int y   = tt % Hl;
    int n   = tt / Hl;
    out[idx] = in[((n * 128 + c) * Hl + y) * Wl + x];
}

// ---------------- fp32 -> bf16 conversion ----------------
__global__ __launch_bounds__(256) void cvt_bf16_k(
    const float* __restrict__ in, __hip_bfloat16* __restrict__ out, int n)
{
    int i = blockIdx.x * 256 + threadIdx.x;
    if (i < n) out[i] = __float2bfloat16(in[i]);
}

// ---------------- pe_w2 [256][128] -> W[n][k] bf16 [128][256] ----------------
__global__ __launch_bounds__(256) void cvt_pew2T_k(
    const float* __restrict__ w, __hip_bfloat16* __restrict__ out)
{
    int n = blockIdx.x, k = threadIdx.x;
    out[n * 256 + k] = __float2bfloat16(w[k * 128 + n]);
}

// ---------------- conv weight rearrange: w[o][i][dy][dx] -> wre[o][(dy*3+dx)*128+i] bf16 ----------------
__global__ __launch_bounds__(256) void convw_k(
    const float* __restrict__ w, __hip_bfloat16* __restrict__ wre)
{
    int o = blockIdx.x;
    for (int idx = threadIdx.x; idx < 1152; idx += 256) {
        int s = idx >> 7, i = idx & 127;
        wre[o * 1152 + idx] = __float2bfloat16(w[(o * 128 + i) * 9 + s]);
    }
}

// ---------------- im2col (shift-major K): A[pix][s*128+c] bf16 ----------------
__global__ __launch_bounds__(256) void im2col_k(
    const float* __restrict__ q, __hip_bfloat16* __restrict__ A)
{
    __shared__ __hip_bfloat16 win[128][3][68];
    int b = blockIdx.x;           // 256 blocks: half-row each
    int y = b >> 1, xb = (b & 1) * 64;
    int t = threadIdx.x;
    int xi = t & 63, cg = t >> 6;
    for (int c = cg; c < 128; c += 4) {
        const float* qc = q + c * HW;
        #pragma unroll
        for (int dy = 0; dy < 3; dy++) {
            int gy = y + dy - 1;
            bool yok = ((unsigned)gy < 128u);
            int gx = xb - 1 + xi;
            float v = (yok && (unsigned)gx < 128u) ? qc[gy * 128 + gx] : 0.f;
            win[c][dy][xi] = __float2bfloat16(v);
            if (xi < 2) {
                int gx2 = xb - 1 + 64 + xi;
                float v2 = (yok && (unsigned)gx2 < 128u) ? qc[gy * 128 + gx2] : 0.f;
                win[c][dy][64 + xi] = __float2bfloat16(v2);
            }
        }
    }
    __syncthreads();
    int p = t >> 2, c0 = (t & 3) * 32;
    size_t pix = (size_t)(y * 128 + xb + p);
    #pragma unroll 1
    for (int s = 0; s < 9; s++) {
        int dy = s / 3, dx = s - dy * 3;
        int wx = p + dx;  // 0..65
        #pragma unroll
        for (int g = 0; g < 4; g++) {
            int c = c0 + g * 8;
            union { __hip_bfloat16 h[8]; uint4 u; } pk;
            #pragma unroll
            for (int j = 0; j < 8; j++) pk.h[j] = win[c + j][dy][wx];
            *(uint4*)&A[pix * 1152 + s * 128 + c] = pk.u;
        }
    }
}

// ---------------- bf16 MFMA GEMM: out[m][n] = act(bias[n] + sum_k X[m][k] W[n][k]) ----------------
// BN = 128 fixed. OUTT: 0 -> bf16 [M][N] row-major; 1 -> fp32 [N][M] transposed (CHW)
template<int BM, int ACT, int OUTT>
__global__ __launch_bounds__(256) void bgemm_k(
    const __hip_bfloat16* __restrict__ X, const __hip_bfloat16* __restrict__ W,
    const float* __restrict__ bias, void* __restrict__ outp,
    int M, int K, int N)
{
    constexpr int ROWS = BM + 128;
    __shared__ __align__(16) __hip_bfloat16 SH[ROWS * 32];
    __hip_bfloat16* As = SH;
    __hip_bfloat16* Bs = SH + BM * 32;
    int t = threadIdx.x;
    int w = t >> 6, lane = t & 63;
    int mb = blockIdx.y * BM, nb = blockIdx.x * 128;
    constexpr int WM = BM / 2;
    constexpr int MI = WM / 16;
    int wm = (w & 1) * WM, wn = (w >> 1) * 64;
    int lm = lane & 15, lq = lane >> 4;
    floatx4 zero = {0.f, 0.f, 0.f, 0.f};
    floatx4 acc[MI][4];
    #pragma unroll
    for (int i = 0; i < MI; i++)
        #pragma unroll
        for (int j = 0; j < 4; j++) acc[i][j] = zero;
    constexpr int ITERS = (ROWS * 4) / 256;
    for (int kb = 0; kb < K; kb += 32) {
        __syncthreads();
        #pragma unroll
        for (int it = 0; it < ITERS; it++) {
            int chunk = it * 256 + t;
            int row = chunk >> 2, ko = (chunk & 3) * 8;
            const __hip_bfloat16* src = (row < BM)
                ? (X + (size_t)(mb + row) * K + kb + ko)
                : (W + (size_t)(nb + row - BM) * K + kb + ko);
            *(uint4*)&SH[chunk * 8] = *(const uint4*)src;
        }
        __syncthreads();
        short8 af[MI], bf[4];
        #pragma unroll
        for (int i = 0; i < MI; i++)
            af[i] = *(const short8*)&As[(wm + i * 16 + lm) * 32 + lq * 8];
        #pragma unroll
        for (int j = 0; j < 4; j++)
            bf[j] = *(const short8*)&Bs[(wn + j * 16 + lm) * 32 + lq * 8];
        #pragma unroll
        for (int i = 0; i < MI; i++)
            #pragma unroll
            for (int j = 0; j < 4; j++)
                acc[i][j] = __builtin_amdgcn_mfma_f32_16x16x32_bf16(af[i], bf[j], acc[i][j], 0, 0, 0);
    }
    #pragma unroll
    for (int i = 0; i < MI; i++) {
        #pragma unroll
        for (int j = 0; j < 4; j++) {
            int n = nb + wn + j * 16 + lm;
            float bv = bias[n];
            #pragma unroll
            for (int r = 0; r < 4; r++) {
                int m = mb + wm + i * 16 + lq * 4 + r;
                float v = acc[i][j][r] + bv;
                if (ACT) v = gelu_exact(v);
                if (OUTT == 0) ((__hip_bfloat16*)outp)[(size_t)m * N + n] = __float2bfloat16(v);
                else           ((float*)outp)[(size_t)n * M + m] = v;
            }
        }
    }
}

// ---------------- instance norm (optionally a+b) over HW per channel ----------------
__global__ __launch_bounds__(256) void inorm_k(
    const float* __restrict__ a, const float* __restrict__ addc, float* __restrict__ out)
{
    int c = blockIdx.x;
    const float* pa = a + (size_t)c * HW;
    const float* pb = addc ? addc + (size_t)c * HW : nullptr;
    const bool hasb = (pb != nullptr);
    float s = 0.f, s2 = 0.f;
    for (int i = threadIdx.x; i < HW; i += 256) {
        float v = hasb ? (pa[i] + pb[i]) : pa[i];
        s += v; s2 += v * v;
    }
    #pragma unroll
    for (int off = 32; off > 0; off >>= 1) {
        s  += __shfl_down(s,  off);
        s2 += __shfl_down(s2, off);
    }
    __shared__ float ls[4], ls2[4], stats[2];
    int wid = threadIdx.x >> 6, lane = threadIdx.x & 63;
    if (lane == 0) { ls[wid] = s; ls2[wid] = s2; }
    __syncthreads();
    if (threadIdx.x == 0) {
        float t = 0.f, t2 = 0.f;
        for (int i = 0; i < 4; i++) { t += ls[i]; t2 += ls2[i]; }
        float mean = t * (1.0f / HW);
        float var  = t2 * (1.0f / HW) - mean * mean;
        stats[0] = mean;
        stats[1] = rsqrtf(var + 1e-5f);
    }
    __syncthreads();
    float mean = stats[0], rstd = stats[1];
    float* po = out + (size_t)c * HW;
    for (int i = threadIdx.x; i < HW; i += 256) {
        float v = hasb ? (pa[i] + pb[i]) : pa[i];
        po[i] = (v - mean) * rstd;
    }
}

// ---------------- offsets + sample-weights per pixel ----------------
__global__ __launch_bounds__(64) void offsw_k(
    const float* __restrict__ q0,
    const float* __restrict__ off_w, const float* __restrict__ off_b,
    const float* __restrict__ sw_w,  const float* __restrict__ sw_b,
    const float* __restrict__ bev_pos,
    float* __restrict__ pts, float* __restrict__ swn, float* __restrict__ height_out)
{
    int pix = blockIdx.x;
    int t = threadIdx.x;
    __shared__ float qv[128];
    __shared__ float raw[32];
    qv[t]      = q0[t * HW + pix];
    qv[t + 64] = q0[(t + 64) * HW + pix];
    __syncthreads();
    if (t < 24) {
        const float* wr = off_w + t * 128;
        float acc = off_b[t];
        for (int k = 0; k < 128; k++) acc += wr[k] * qv[k];
        float sv = 1.f / (1.f + expf(-acc));
        int p = t / 3, d = t - p * 3;
        float lim = (d == 2) ? (4.0f + 1e-6f) : (0.25f + 1e-6f);
        float offv = sv * 2.f * lim - lim;
        const float pcmin[3] = {-50.f, -50.f, -4.f};
        const float rng[3]   = {100.f, 100.f, 8.f};
        float refv = bev_pos[pix * 3 + d] * rng[d] + pcmin[d];
        pts[(pix * 8 + p) * 3 + d] = refv + offv;
        if (d == 2) height_out[p * HW + pix] = offv;
    } else if (t < 56) {
        int r = t - 24;
        const float* wr = sw_w + r * 128;
        float acc = sw_b[r];
        for (int k = 0; k < 128; k++) acc += wr[k] * qv[k];
        raw[r] = acc;
    }
    __syncthreads();
    if (t < 8) {
        float m = raw[t * 4];
        #pragma unroll
        for (int l = 1; l < 4; l++) m = fmaxf(m, raw[t * 4 + l]);
        float e[4], sum = 0.f;
        #pragma unroll
        for (int l = 0; l < 4; l++) { e[l] = expf(raw[t * 4 + l] - m); sum += e[l]; }
        float inv = 1.f / sum;
        #pragma unroll
        for (int l = 0; l < 4; l++) swn[(pix * 8 + t) * 4 + l] = e[l] * inv;
    }
}

// ---------------- PE hidden layer: h[row][256] bf16 (pts pre-offset by caller) ----------------
__global__ __launch_bounds__(256) void pe_hidden_k(
    const float* __restrict__ pts, const float* __restrict__ pe_w1,
    const float* __restrict__ pe_b1, __hip_bfloat16* __restrict__ h)
{
    __shared__ float w1s[768];
    __shared__ float b1s[256];
    int t = threadIdx.x;
    for (int i = t; i < 768; i += 256) w1s[i] = pe_w1[i];
    b1s[t] = pe_b1[t];
    __syncthreads();
    int r = t >> 5, jg = (t & 31) * 8;
    size_t row = (size_t)blockIdx.x * 8 + r;
    float rn0 = (pts[row * 3 + 0] + 50.f) * 0.01f;
    float rn1 = (pts[row * 3 + 1] + 50.f) * 0.01f;
    float rn2 = (pts[row * 3 + 2] + 4.f) * 0.125f;
    union { __hip_bfloat16 hh[8]; uint4 u; } pk;
    #pragma unroll
    for (int j = 0; j < 8; j++) {
        int jj = jg + j;
        float v = b1s[jj] + rn0 * w1s[jj] + rn1 * w1s[256 + jj] + rn2 * w1s[512 + jj];
        pk.hh[j] = __float2bfloat16(fmaxf(v, 0.f));
    }
    *(uint4*)&h[row * 256 + jg] = pk.u;
}

// ---------------- sampling: phase-1 per-combo projection + cull, phase-2 gather ----------------
// sf already contains PE result (bf16); we accumulate taps on top.
__global__ __launch_bounds__(128) void sample_k(
    const float* __restrict__ featT, const float* __restrict__ pts,
    const float* __restrict__ swn,   const float* __restrict__ l2i,
    __hip_bfloat16* __restrict__ sf)
{
    int pix = blockIdx.x;
    int t = threadIdx.x;
    __shared__ float pts_s[24];
    __shared__ float swl_s[32];
    __shared__ float M[96];
    __shared__ __align__(16) int   offs[8][24][4];
    __shared__ __align__(16) float wts[8][24][4];
    __shared__ int cnt[8];
    if (t < 96) M[t] = l2i[t];
    if (t < 24) pts_s[t] = pts[pix * 24 + t];
    if (t < 32) swl_s[t] = swn[pix * 32 + t];
    if (t < 8)  cnt[t] = 0;
    __syncthreads();

    // preload PE row while phase-1 computes
    float acc[8];
    #pragma unroll
    for (int p = 0; p < 8; p++)
        acc[p] = __bfloat162float(sf[(size_t)pix * 1024 + p * 128 + t]);

    const int lHt[4] = {32, 16, 8, 4}, lWt[4] = {88, 44, 22, 11};
    const int loff[4] = {0, 2162688, 2703360, 2838528};
    // phase 1: 192 combos across 128 threads
    for (int cb = t; cb < 192; cb += 128) {
        int p = cb / 24;
        int rr = cb - p * 24;
        int n = rr >> 2, l = rr & 3;
        float X = pts_s[p * 3], Y = pts_s[p * 3 + 1], Z = pts_s[p * 3 + 2];
        const float* Mn = &M[n * 16];
        float zc = Mn[8] * X + Mn[9] * Y + Mn[10] * Z + Mn[11];
        if (zc > 1e-5f) {
            float inv = 1.f / zc;
            float xn = (Mn[0] * X + Mn[1] * Y + Mn[2] * Z + Mn[3]) * inv * (1.f / 704.f);
            float yn = (Mn[4] * X + Mn[5] * Y + Mn[6] * Z + Mn[7]) * inv * (1.f / 256.f);
            int Wl = lWt[l], Hl = lHt[l];
            float px = xn * Wl - 0.5f, py = yn * Hl - 0.5f;
            px = fminf(fmaxf(px, -2.f), (float)(Wl + 1));
            py = fminf(fmaxf(py, -2.f), (float)(Hl + 1));
            float x0f = floorf(px), y0f = floorf(py);
            float wx = px - x0f, wy = py - y0f;
            int x0 = (int)x0f, y0 = (int)y0f;
            bool xi0 = (unsigned)x0 < (unsigned)Wl, xi1 = (unsigned)(x0 + 1) < (unsigned)Wl;
            bool yi0 = (unsigned)y0 < (unsigned)Hl, yi1 = (unsigned)(y0 + 1) < (unsigned)Hl;
            if ((xi0 || xi1) && (yi0 || yi1)) {
                float wl = swl_s[p * 4 + l];
                float w00 = wl * (1.f - wx) * (1.f - wy) * (float)(xi0 && yi0);
                float w10 = wl * wx * (1.f - wy)         * (float)(xi1 && yi0);
                float w01 = wl * (1.f - wx) * wy         * (float)(xi0 && yi1);
                float w11 = wl * wx * wy                 * (float)(xi1 && yi1);
                int x0c = min(max(x0, 0), Wl - 1), x1c = min(max(x0 + 1, 0), Wl - 1);
                int y0c = min(max(y0, 0), Hl - 1), y1c = min(max(y0 + 1, 0), Hl - 1);
                int base = loff[l] + n * Hl * Wl * 128;
                int idx = atomicAdd(&cnt[p], 1);
                offs[p][idx][0] = base + (y0c * Wl + x0c) * 128;
                offs[p][idx][1] = base + (y0c * Wl + x1c) * 128;
                offs[p][idx][2] = base + (y1c * Wl + x0c) * 128;
                offs[p][idx][3] = base + (y1c * Wl + x1c) * 128;
                wts[p][idx][0] = w00; wts[p][idx][1] = w10;
                wts[p][idx][2] = w01; wts[p][idx][3] = w11;
            }
        }
    }
    __syncthreads();

    // phase 2: gather
    #pragma unroll 1
    for (int p = 0; p < 8; p++) {
        int np = cnt[p];
        float a = acc[p];
        #pragma unroll 1
        for (int i = 0; i < np; i++) {
            int4   o = *(const int4*)&offs[p][i][0];
            float4 w = *(const float4*)&wts[p][i][0];
            float f0 = featT[o.x + t];
            float f1 = featT[o.y + t];
            float f2 = featT[o.z + t];
            float f3 = featT[o.w + t];
            a += w.x * f0 + w.y * f1 + w.z * f2 + w.w * f3;
        }
        acc[p] = a;
    }
    #pragma unroll
    for (int p = 0; p < 8; p++)
        sf[(size_t)pix * 1024 + p * 128 + t] = __float2bfloat16(acc[p]);
}

extern "C" void kernel_launch(void* const* d_in, const int* in_sizes, int n_in,
                              void* d_out, int out_size, void* d_ws, size_t ws_size,
                              hipStream_t stream)
{
    const float* feat[4] = {(const float*)d_in[0], (const float*)d_in[1],
                            (const float*)d_in[2], (const float*)d_in[3]};
    const float* l2i       = (const float*)d_in[4];
    const float* bev_query = (const float*)d_in[5];
    const float* bev_pos   = (const float*)d_in[6];
    const float* in_w  = (const float*)d_in[7];  const float* in_b  = (const float*)d_in[8];
    const float* off_w = (const float*)d_in[9];  const float* off_b = (const float*)d_in[10];
    const float* sw_w  = (const float*)d_in[11]; const float* sw_b  = (const float*)d_in[12];
    const float* pe_w1 = (const float*)d_in[13]; const float* pe_b1 = (const float*)d_in[14];
    const float* pe_w2 = (const float*)d_in[15]; const float* pe_b2 = (const float*)d_in[16];
    const float* mid_w1 = (const float*)d_in[17]; const float* mid_b1 = (const float*)d_in[18];
    const float* mid_w2 = (const float*)d_in[19]; const float* mid_b2 = (const float*)d_in[20];
    const float* mid_w3 = (const float*)d_in[21]; const float* mid_b3 = (const float*)d_in[22];
    const float* out_w  = (const float*)d_in[23]; const float* out_b  = (const float*)d_in[24];

    float* ws = (float*)d_ws;
    // workspace layout (floats), total 28,423,168 fl = 113.7 MB
    float* fT  = ws;                    // 2,872,320 : transposed feats
    float* Bb  = ws + 2872320;          // 2,097,152 : conv out / m3 (CHW)
    float* Cb  = Bb + 2097152;          // 2,097,152 : q0 / conv2 out
    float* Gb  = Cb + 2097152;          // 2,097,152 : q1 (CHW)
    float* Dp  = Gb + 2097152;          //   393,216 : pts
    float* Eb  = Dp + 393216;           //   524,288 : swn
    float* Af  = Eb + 524288;           // 9,437,184 : im2col A bf16 | sf bf16 (disjoint lifetimes)
    __hip_bfloat16* Aim = (__hip_bfloat16*)Af;
    __hip_bfloat16* sfb = (__hip_bfloat16*)Af;      // 131072 x 128 bf16 = 8,388,608 fl
    float* M1f = Af + 9437184;          // 4,194,304 : m1 bf16 | (with M2f) chunked PE hidden
    __hip_bfloat16* m1b = (__hip_bfloat16*)M1f;
    __hip_bfloat16* hb  = (__hip_bfloat16*)M1f;     // 65536 x 256 bf16 = 8,388,608 fl (M1f+M2f, dead before m1/m2)
    float* M2f = M1f + 4194304;         // 4,194,304 : m2 bf16
    __hip_bfloat16* m2b = (__hip_bfloat16*)M2f;
    float* Wc  = M2f + 4194304;         //    73,728 : conv weights bf16
    __hip_bfloat16* Wcv = (__hip_bfloat16*)Wc;
    float* W1f = Wc + 73728;            //   262,144
    __hip_bfloat16* Wb1 = (__hip_bfloat16*)W1f;
    float* W2f = W1f + 262144;          //   131,072
    __hip_bfloat16* Wb2 = (__hip_bfloat16*)W2f;
    float* W3f = W2f + 131072;          //    32,768
    __hip_bfloat16* Wb3 = (__hip_bfloat16*)W3f;
    float* WPf = W3f + 32768;           //    16,384 : pe_w2^T bf16
    __hip_bfloat16* Wpe = (__hip_bfloat16*)WPf;

    float* q_out = (float*)d_out;
    float* h_out = q_out + 2097152;

    const int lH[4] = {32, 16, 8, 4}, lW[4] = {88, 44, 22, 11};
    const int loff[4] = {0, 2162688, 2703360, 2838528};
    for (int l = 0; l < 4; l++) {
        int total = 6 * lH[l] * lW[l] * 128;
        feat_transpose_k<<<(total + 255) / 256, 256, 0, stream>>>(feat[l], fT + loff[l], lH[l], lW[l], total);
    }
    // weight prep
    cvt_bf16_k<<<(524288 + 255) / 256, 256, 0, stream>>>(mid_w1, Wb1, 524288);
    cvt_bf16_k<<<(262144 + 255) / 256, 256, 0, stream>>>(mid_w2, Wb2, 262144);
    cvt_bf16_k<<<(65536  + 255) / 256, 256, 0, stream>>>(mid_w3, Wb3, 65536);
    cvt_pew2T_k<<<128, 256, 0, stream>>>(pe_w2, Wpe);

    // conv1: q0 = inorm(bev_query + conv3x3(bev_query))
    convw_k<<<128, 256, 0, stream>>>(in_w, Wcv);
    im2col_k<<<256, 256, 0, stream>>>(bev_query, Aim);
    bgemm_k<64, 0, 1><<<dim3(1, 256), 256, 0, stream>>>(Aim, Wcv, in_b, Bb, HW, 1152, 128);
    inorm_k<<<128, 256, 0, stream>>>(Bb, bev_query, Cb);

    // offsets, sample weights, pts, height
    offsw_k<<<HW, 64, 0, stream>>>(Cb, off_w, off_b, sw_w, sw_b, bev_pos, Dp, Eb, h_out);

    // PE: hidden (bf16) then MFMA GEMM into sf, in 2 row-chunks of 65536 (hb fits M1f+M2f)
    for (int ch = 0; ch < 2; ch++) {
        size_t row0 = (size_t)ch * 65536;
        pe_hidden_k<<<8192, 256, 0, stream>>>(Dp + row0 * 3, pe_w1, pe_b1, hb);
        bgemm_k<128, 0, 0><<<dim3(1, 512), 256, 0, stream>>>(
            hb, Wpe, pe_b2, sfb + row0 * 128, 65536, 256, 128);
    }

    // sampling accumulates taps onto sf
    sample_k<<<HW, 128, 0, stream>>>(fT, Dp, Eb, l2i, sfb);

    // mid MLP (bf16 MFMA): 1024 -> 512 gelu -> 512 gelu -> 128 linear (CHW fp32)
    bgemm_k<128, 1, 0><<<dim3(4, 128), 256, 0, stream>>>(sfb, Wb1, mid_b1, m1b, HW, 1024, 512);
    bgemm_k<128, 1, 0><<<dim3(4, 128), 256, 0, stream>>>(m1b, Wb2, mid_b2, m2b, HW, 512, 512);
    bgemm_k<64, 0, 1><<<dim3(1, 256), 256, 0, stream>>>(m2b, Wb3, mid_b3, Bb, HW, 512, 128);

    // q1 = inorm(q0 + m)
    inorm_k<<<128, 256, 0, stream>>>(Cb, Bb, Gb);

    // conv2: q = inorm(q1 + conv3x3(q1))
    convw_k<<<128, 256, 0, stream>>>(out_w, Wcv);
    im2col_k<<<256, 256, 0, stream>>>(Gb, Aim);
    bgemm_k<64, 0, 1><<<dim3(1, 256), 256, 0, stream>>>(Aim, Wcv, out_b, Cb, HW, 1152, 128);
    inorm_k<<<128, 256, 0, stream>>>(Cb, Gb, q_out);
}

// Round 5
// 594.219 us; speedup vs baseline: 3.5416x; 1.1874x over previous
//
#include <hip/hip_runtime.h>
#include <hip/hip_bf16.h>
#include <math.h>

#define HW 16384   // 128*128 bev pixels

typedef __attribute__((ext_vector_type(8))) short short8;
typedef __attribute__((ext_vector_type(4))) float floatx4;

__device__ __forceinline__ float gelu_exact(float x){
    return 0.5f * x * (1.0f + erff(x * 0.7071067811865475f));
}

// ---------------- feat transpose: (N,C,H,W) fp32 -> (N,H,W,C) bf16 ----------------
__global__ __launch_bounds__(256) void feat_transpose_k(
    const float* __restrict__ in, __hip_bfloat16* __restrict__ out, int Hl, int Wl, int total)
{
    int idx = blockIdx.x * 256 + threadIdx.x;
    if (idx >= total) return;
    int c   = idx & 127;
    int pix = idx >> 7;
    int x   = pix % Wl;
    int tt  = pix / Wl;
    int y   = tt % Hl;
    int n   = tt / Hl;
    out[idx] = __float2bfloat16(in[((n * 128 + c) * Hl + y) * Wl + x]);
}

// ---------------- fp32 -> bf16 conversion ----------------
__global__ __launch_bounds__(256) void cvt_bf16_k(
    const float* __restrict__ in, __hip_bfloat16* __restrict__ out, int n)
{
    int i = blockIdx.x * 256 + threadIdx.x;
    if (i < n) out[i] = __float2bfloat16(in[i]);
}

// ---------------- pe_w2 [256][128] -> W[n][k] bf16 [128][256] ----------------
__global__ __launch_bounds__(256) void cvt_pew2T_k(
    const float* __restrict__ w, __hip_bfloat16* __restrict__ out)
{
    int n = blockIdx.x, k = threadIdx.x;
    out[n * 256 + k] = __float2bfloat16(w[k * 128 + n]);
}

// ---------------- conv weight rearrange: w[o][i][dy][dx] -> wre[o][(dy*3+dx)*128+i] bf16 ----------------
__global__ __launch_bounds__(256) void convw_k(
    const float* __restrict__ w, __hip_bfloat16* __restrict__ wre)
{
    int o = blockIdx.x;
    for (int idx = threadIdx.x; idx < 1152; idx += 256) {
        int s = idx >> 7, i = idx & 127;
        wre[o * 1152 + idx] = __float2bfloat16(w[(o * 128 + i) * 9 + s]);
    }
}

// ---------------- CHW fp32 [128][128^2] -> padded HWC bf16 [130][130][128] (interior) ----------------
// border must be pre-zeroed by caller (hipMemsetAsync once per launch).
__global__ __launch_bounds__(256) void chw2hwc_pad_k(
    const float* __restrict__ q, __hip_bfloat16* __restrict__ out)
{
    __shared__ float tile[128][65];
    int b = blockIdx.x;            // 256 blocks: y = b>>1, x0 = (b&1)*64
    int y = b >> 1, x0 = (b & 1) * 64;
    int t = threadIdx.x;
    int xi = t & 63, c0 = t >> 6;
    for (int c = c0; c < 128; c += 4)
        tile[c][xi] = q[c * HW + y * 128 + x0 + xi];
    __syncthreads();
    int xp = t >> 2, cg = (t & 3) * 32;
    __hip_bfloat16* dst = out + ((size_t)(y + 1) * 130 + (x0 + 1 + xp)) * 128;
    #pragma unroll
    for (int g = 0; g < 4; g++) {
        int c = cg + g * 8;
        union { __hip_bfloat16 h[8]; uint4 u; } pk;
        #pragma unroll
        for (int j = 0; j < 8; j++) pk.h[j] = __float2bfloat16(tile[c + j][xp]);
        *(uint4*)&dst[c] = pk.u;
    }
}

// ---------------- bf16 MFMA GEMM: out[m][n] = act(bias[n] + sum_k X[m][k] W[n][k]) ----------------
// BN = 128 fixed. OUTT: 0 -> bf16 [M][N]; 1 -> fp32 [N][M] (CHW).
// CONV: X is padded HWC bf16 [130][130][128]; k = s*128+c, tile = half BEV row (BM must be 64).
template<int BM, int ACT, int OUTT, int CONV>
__global__ __launch_bounds__(256) void bgemm_k(
    const __hip_bfloat16* __restrict__ X, const __hip_bfloat16* __restrict__ W,
    const float* __restrict__ bias, void* __restrict__ outp,
    int M, int K, int N)
{
    constexpr int ROWS = BM + 128;
    __shared__ __align__(16) __hip_bfloat16 SH[ROWS * 32];
    __hip_bfloat16* As = SH;
    __hip_bfloat16* Bs = SH + BM * 32;
    int t = threadIdx.x;
    int w = t >> 6, lane = t & 63;
    int mb = blockIdx.y * BM, nb = blockIdx.x * 128;
    int cy = mb >> 7, cx = mb & 127;   // conv tile coords (CONV only)
    constexpr int WM = BM / 2;
    constexpr int MI = WM / 16;
    int wm = (w & 1) * WM, wn = (w >> 1) * 64;
    int lm = lane & 15, lq = lane >> 4;
    floatx4 zero = {0.f, 0.f, 0.f, 0.f};
    floatx4 acc[MI][4];
    #pragma unroll
    for (int i = 0; i < MI; i++)
        #pragma unroll
        for (int j = 0; j < 4; j++) acc[i][j] = zero;
    constexpr int ITERS = (ROWS * 4) / 256;
    for (int kb = 0; kb < K; kb += 32) {
        int s = kb >> 7;
        int dyi = s / 3, dxi = s - dyi * 3;   // tap indices 0..2 (CONV only)
        __syncthreads();
        #pragma unroll
        for (int it = 0; it < ITERS; it++) {
            int chunk = it * 256 + t;
            int row = chunk >> 2, ko = (chunk & 3) * 8;
            const __hip_bfloat16* src;
            if (row < BM) {
                if (CONV)
                    src = X + (((size_t)(cy + dyi) * 130) + (cx + dxi + row)) * 128 + (kb & 127) + ko;
                else
                    src = X + (size_t)(mb + row) * K + kb + ko;
            } else {
                src = W + (size_t)(nb + row - BM) * K + kb + ko;
            }
            *(uint4*)&SH[chunk * 8] = *(const uint4*)src;
        }
        __syncthreads();
        short8 af[MI], bf[4];
        #pragma unroll
        for (int i = 0; i < MI; i++)
            af[i] = *(const short8*)&As[(wm + i * 16 + lm) * 32 + lq * 8];
        #pragma unroll
        for (int j = 0; j < 4; j++)
            bf[j] = *(const short8*)&Bs[(wn + j * 16 + lm) * 32 + lq * 8];
        #pragma unroll
        for (int i = 0; i < MI; i++)
            #pragma unroll
            for (int j = 0; j < 4; j++)
                acc[i][j] = __builtin_amdgcn_mfma_f32_16x16x32_bf16(af[i], bf[j], acc[i][j], 0, 0, 0);
    }
    #pragma unroll
    for (int i = 0; i < MI; i++) {
        #pragma unroll
        for (int j = 0; j < 4; j++) {
            int n = nb + wn + j * 16 + lm;
            float bv = bias[n];
            #pragma unroll
            for (int r = 0; r < 4; r++) {
                int m = mb + wm + i * 16 + lq * 4 + r;
                float v = acc[i][j][r] + bv;
                if (ACT) v = gelu_exact(v);
                if (OUTT == 0) ((__hip_bfloat16*)outp)[(size_t)m * N + n] = __float2bfloat16(v);
                else           ((float*)outp)[(size_t)n * M + m] = v;
            }
        }
    }
}

// ---------------- instance norm (optionally a+b) over HW per channel ----------------
__global__ __launch_bounds__(256) void inorm_k(
    const float* __restrict__ a, const float* __restrict__ addc, float* __restrict__ out)
{
    int c = blockIdx.x;
    const float* pa = a + (size_t)c * HW;
    const float* pb = addc ? addc + (size_t)c * HW : nullptr;
    const bool hasb = (pb != nullptr);
    float s = 0.f, s2 = 0.f;
    for (int i = threadIdx.x; i < HW; i += 256) {
        float v = hasb ? (pa[i] + pb[i]) : pa[i];
        s += v; s2 += v * v;
    }
    #pragma unroll
    for (int off = 32; off > 0; off >>= 1) {
        s  += __shfl_down(s,  off);
        s2 += __shfl_down(s2, off);
    }
    __shared__ float ls[4], ls2[4], stats[2];
    int wid = threadIdx.x >> 6, lane = threadIdx.x & 63;
    if (lane == 0) { ls[wid] = s; ls2[wid] = s2; }
    __syncthreads();
    if (threadIdx.x == 0) {
        float t = 0.f, t2 = 0.f;
        for (int i = 0; i < 4; i++) { t += ls[i]; t2 += ls2[i]; }
        float mean = t * (1.0f / HW);
        float var  = t2 * (1.0f / HW) - mean * mean;
        stats[0] = mean;
        stats[1] = rsqrtf(var + 1e-5f);
    }
    __syncthreads();
    float mean = stats[0], rstd = stats[1];
    float* po = out + (size_t)c * HW;
    for (int i = threadIdx.x; i < HW; i += 256) {
        float v = hasb ? (pa[i] + pb[i]) : pa[i];
        po[i] = (v - mean) * rstd;
    }
}

// ---------------- offsets + sample-weights per pixel (reads padded HWC bf16 q0) ----------------
__global__ __launch_bounds__(64) void offsw_k(
    const __hip_bfloat16* __restrict__ qT,
    const float* __restrict__ off_w, const float* __restrict__ off_b,
    const float* __restrict__ sw_w,  const float* __restrict__ sw_b,
    const float* __restrict__ bev_pos,
    float* __restrict__ pts, float* __restrict__ swn, float* __restrict__ height_out)
{
    int pix = blockIdx.x;
    int t = threadIdx.x;
    __shared__ float qv[128];
    __shared__ float raw[32];
    int y = pix >> 7, x = pix & 127;
    const __hip_bfloat16* qrow = qT + ((size_t)(y + 1) * 130 + (x + 1)) * 128;
    qv[t]      = __bfloat162float(qrow[t]);
    qv[t + 64] = __bfloat162float(qrow[t + 64]);
    __syncthreads();
    if (t < 24) {
        const float* wr = off_w + t * 128;
        float acc = off_b[t];
        for (int k = 0; k < 128; k++) acc += wr[k] * qv[k];
        float sv = 1.f / (1.f + expf(-acc));
        int p = t / 3, d = t - p * 3;
        float lim = (d == 2) ? (4.0f + 1e-6f) : (0.25f + 1e-6f);
        float offv = sv * 2.f * lim - lim;
        const float pcmin[3] = {-50.f, -50.f, -4.f};
        const float rng[3]   = {100.f, 100.f, 8.f};
        float refv = bev_pos[pix * 3 + d] * rng[d] + pcmin[d];
        pts[(pix * 8 + p) * 3 + d] = refv + offv;
        if (d == 2) height_out[p * HW + pix] = offv;
    } else if (t < 56) {
        int r = t - 24;
        const float* wr = sw_w + r * 128;
        float acc = sw_b[r];
        for (int k = 0; k < 128; k++) acc += wr[k] * qv[k];
        raw[r] = acc;
    }
    __syncthreads();
    if (t < 8) {
        float m = raw[t * 4];
        #pragma unroll
        for (int l = 1; l < 4; l++) m = fmaxf(m, raw[t * 4 + l]);
        float e[4], sum = 0.f;
        #pragma unroll
        for (int l = 0; l < 4; l++) { e[l] = expf(raw[t * 4 + l] - m); sum += e[l]; }
        float inv = 1.f / sum;
        #pragma unroll
        for (int l = 0; l < 4; l++) swn[(pix * 8 + t) * 4 + l] = e[l] * inv;
    }
}

// ---------------- PE hidden layer: h[row][256] bf16 ----------------
__global__ __launch_bounds__(256) void pe_hidden_k(
    const float* __restrict__ pts, const float* __restrict__ pe_w1,
    const float* __restrict__ pe_b1, __hip_bfloat16* __restrict__ h)
{
    __shared__ float w1s[768];
    __shared__ float b1s[256];
    int t = threadIdx.x;
    for (int i = t; i < 768; i += 256) w1s[i] = pe_w1[i];
    b1s[t] = pe_b1[t];
    __syncthreads();
    int r = t >> 5, jg = (t & 31) * 8;
    size_t row = (size_t)blockIdx.x * 8 + r;
    float rn0 = (pts[row * 3 + 0] + 50.f) * 0.01f;
    float rn1 = (pts[row * 3 + 1] + 50.f) * 0.01f;
    float rn2 = (pts[row * 3 + 2] + 4.f) * 0.125f;
    union { __hip_bfloat16 hh[8]; uint4 u; } pk;
    #pragma unroll
    for (int j = 0; j < 8; j++) {
        int jj = jg + j;
        float v = b1s[jj] + rn0 * w1s[jj] + rn1 * w1s[256 + jj] + rn2 * w1s[512 + jj];
        pk.hh[j] = __float2bfloat16(fmaxf(v, 0.f));
    }
    *(uint4*)&h[row * 256 + jg] = pk.u;
}

// ---------------- sampling: phase-1 per-combo projection + cull, phase-2 gather ----------------
// featT is bf16 now. sf already contains PE result; accumulate taps on top.
__global__ __launch_bounds__(128) void sample_k(
    const __hip_bfloat16* __restrict__ featT, const float* __restrict__ pts,
    const float* __restrict__ swn,   const float* __restrict__ l2i,
    __hip_bfloat16* __restrict__ sf)
{
    int pix = blockIdx.x;
    int t = threadIdx.x;
    __shared__ float pts_s[24];
    __shared__ float swl_s[32];
    __shared__ float M[96];
    __shared__ __align__(16) int   offs[8][24][4];
    __shared__ __align__(16) float wts[8][24][4];
    __shared__ int cnt[8];
    if (t < 96) M[t] = l2i[t];
    if (t < 24) pts_s[t] = pts[pix * 24 + t];
    if (t < 32) swl_s[t] = swn[pix * 32 + t];
    if (t < 8)  cnt[t] = 0;
    __syncthreads();

    float acc[8];
    #pragma unroll
    for (int p = 0; p < 8; p++)
        acc[p] = __bfloat162float(sf[(size_t)pix * 1024 + p * 128 + t]);

    const int lHt[4] = {32, 16, 8, 4}, lWt[4] = {88, 44, 22, 11};
    const int loff[4] = {0, 2162688, 2703360, 2838528};
    for (int cb = t; cb < 192; cb += 128) {
        int p = cb / 24;
        int rr = cb - p * 24;
        int n = rr >> 2, l = rr & 3;
        float X = pts_s[p * 3], Y = pts_s[p * 3 + 1], Z = pts_s[p * 3 + 2];
        const float* Mn = &M[n * 16];
        float zc = Mn[8] * X + Mn[9] * Y + Mn[10] * Z + Mn[11];
        if (zc > 1e-5f) {
            float inv = 1.f / zc;
            float xn = (Mn[0] * X + Mn[1] * Y + Mn[2] * Z + Mn[3]) * inv * (1.f / 704.f);
            float yn = (Mn[4] * X + Mn[5] * Y + Mn[6] * Z + Mn[7]) * inv * (1.f / 256.f);
            int Wl = lWt[l], Hl = lHt[l];
            float px = xn * Wl - 0.5f, py = yn * Hl - 0.5f;
            px = fminf(fmaxf(px, -2.f), (float)(Wl + 1));
            py = fminf(fmaxf(py, -2.f), (float)(Hl + 1));
            float x0f = floorf(px), y0f = floorf(py);
            float wx = px - x0f, wy = py - y0f;
            int x0 = (int)x0f, y0 = (int)y0f;
            bool xi0 = (unsigned)x0 < (unsigned)Wl, xi1 = (unsigned)(x0 + 1) < (unsigned)Wl;
            bool yi0 = (unsigned)y0 < (unsigned)Hl, yi1 = (unsigned)(y0 + 1) < (unsigned)Hl;
            if ((xi0 || xi1) && (yi0 || yi1)) {
                float wl = swl_s[p * 4 + l];
                float w00 = wl * (1.f - wx) * (1.f - wy) * (float)(xi0 && yi0);
                float w10 = wl * wx * (1.f - wy)         * (float)(xi1 && yi0);
                float w01 = wl * (1.f - wx) * wy         * (float)(xi0 && yi1);
                float w11 = wl * wx * wy                 * (float)(xi1 && yi1);
                int x0c = min(max(x0, 0), Wl - 1), x1c = min(max(x0 + 1, 0), Wl - 1);
                int y0c = min(max(y0, 0), Hl - 1), y1c = min(max(y0 + 1, 0), Hl - 1);
                int base = loff[l] + n * Hl * Wl * 128;
                int idx = atomicAdd(&cnt[p], 1);
                offs[p][idx][0] = base + (y0c * Wl + x0c) * 128;
                offs[p][idx][1] = base + (y0c * Wl + x1c) * 128;
                offs[p][idx][2] = base + (y1c * Wl + x0c) * 128;
                offs[p][idx][3] = base + (y1c * Wl + x1c) * 128;
                wts[p][idx][0] = w00; wts[p][idx][1] = w10;
                wts[p][idx][2] = w01; wts[p][idx][3] = w11;
            }
        }
    }
    __syncthreads();

    #pragma unroll 1
    for (int p = 0; p < 8; p++) {
        int np = cnt[p];
        float a = acc[p];
        #pragma unroll 1
        for (int i = 0; i < np; i++) {
            int4   o = *(const int4*)&offs[p][i][0];
            float4 w = *(const float4*)&wts[p][i][0];
            float f0 = __bfloat162float(featT[o.x + t]);
            float f1 = __bfloat162float(featT[o.y + t]);
            float f2 = __bfloat162float(featT[o.z + t]);
            float f3 = __bfloat162float(featT[o.w + t]);
            a += w.x * f0 + w.y * f1 + w.z * f2 + w.w * f3;
        }
        acc[p] = a;
    }
    #pragma unroll
    for (int p = 0; p < 8; p++)
        sf[(size_t)pix * 1024 + p * 128 + t] = __float2bfloat16(acc[p]);
}

extern "C" void kernel_launch(void* const* d_in, const int* in_sizes, int n_in,
                              void* d_out, int out_size, void* d_ws, size_t ws_size,
                              hipStream_t stream)
{
    const float* feat[4] = {(const float*)d_in[0], (const float*)d_in[1],
                            (const float*)d_in[2], (const float*)d_in[3]};
    const float* l2i       = (const float*)d_in[4];
    const float* bev_query = (const float*)d_in[5];
    const float* bev_pos   = (const float*)d_in[6];
    const float* in_w  = (const float*)d_in[7];  const float* in_b  = (const float*)d_in[8];
    const float* off_w = (const float*)d_in[9];  const float* off_b = (const float*)d_in[10];
    const float* sw_w  = (const float*)d_in[11]; const float* sw_b  = (const float*)d_in[12];
    const float* pe_w1 = (const float*)d_in[13]; const float* pe_b1 = (const float*)d_in[14];
    const float* pe_w2 = (const float*)d_in[15]; const float* pe_b2 = (const float*)d_in[16];
    const float* mid_w1 = (const float*)d_in[17]; const float* mid_b1 = (const float*)d_in[18];
    const float* mid_w2 = (const float*)d_in[19]; const float* mid_b2 = (const float*)d_in[20];
    const float* mid_w3 = (const float*)d_in[21]; const float* mid_b3 = (const float*)d_in[22];
    const float* out_w  = (const float*)d_in[23]; const float* out_b  = (const float*)d_in[24];

    float* ws = (float*)d_ws;
    // workspace layout (floats), total 27,020,032 fl = 108.1 MB
    float* fTf = ws;                    // 1,436,160 : transposed feats bf16 (2,872,320 elems)
    __hip_bfloat16* fT = (__hip_bfloat16*)fTf;
    float* Bb  = fTf + 1436160;         // 2,097,152 : conv out / m3 (CHW)
    float* Cb  = Bb + 2097152;          // 2,097,152 : q0 / conv2 out
    float* Gb  = Cb + 2097152;          // 2,097,152 : q1 (CHW)
    float* Dp  = Gb + 2097152;          //   393,216 : pts
    float* Eb  = Dp + 393216;           //   524,288 : swn
    float* QTf = Eb + 524288;           // 1,081,600 : padded HWC bf16 (130*130*128), serial reuse
    __hip_bfloat16* qT = (__hip_bfloat16*)QTf;
    float* SFf = QTf + 1081600;         // 8,388,608 : sf bf16 131072x128
    __hip_bfloat16* sfb = (__hip_bfloat16*)SFf;
    float* M1f = SFf + 8388608;         // 4,194,304 : m1 bf16 | (with M2f) chunked PE hidden
    __hip_bfloat16* m1b = (__hip_bfloat16*)M1f;
    __hip_bfloat16* hb  = (__hip_bfloat16*)M1f;     // 65536 x 256 bf16 (M1f+M2f)
    float* M2f = M1f + 4194304;         // 4,194,304 : m2 bf16
    __hip_bfloat16* m2b = (__hip_bfloat16*)M2f;
    float* Wc  = M2f + 4194304;         //    73,728 : conv weights bf16
    __hip_bfloat16* Wcv = (__hip_bfloat16*)Wc;
    float* W1f = Wc + 73728;            //   262,144
    __hip_bfloat16* Wb1 = (__hip_bfloat16*)W1f;
    float* W2f = W1f + 262144;          //   131,072
    __hip_bfloat16* Wb2 = (__hip_bfloat16*)W2f;
    float* W3f = W2f + 131072;          //    32,768
    __hip_bfloat16* Wb3 = (__hip_bfloat16*)W3f;
    float* WPf = W3f + 32768;           //    16,384 : pe_w2^T bf16
    __hip_bfloat16* Wpe = (__hip_bfloat16*)WPf;

    float* q_out = (float*)d_out;
    float* h_out = q_out + 2097152;

    // zero padded HWC buffer border once (interior overwritten by each fill)
    hipMemsetAsync(qT, 0, (size_t)130 * 130 * 128 * sizeof(__hip_bfloat16), stream);

    const int lH[4] = {32, 16, 8, 4}, lW[4] = {88, 44, 22, 11};
    const int loff[4] = {0, 2162688, 2703360, 2838528};
    for (int l = 0; l < 4; l++) {
        int total = 6 * lH[l] * lW[l] * 128;
        feat_transpose_k<<<(total + 255) / 256, 256, 0, stream>>>(feat[l], fT + loff[l], lH[l], lW[l], total);
    }
    // weight prep
    cvt_bf16_k<<<(524288 + 255) / 256, 256, 0, stream>>>(mid_w1, Wb1, 524288);
    cvt_bf16_k<<<(262144 + 255) / 256, 256, 0, stream>>>(mid_w2, Wb2, 262144);
    cvt_bf16_k<<<(65536  + 255) / 256, 256, 0, stream>>>(mid_w3, Wb3, 65536);
    cvt_pew2T_k<<<128, 256, 0, stream>>>(pe_w2, Wpe);

    // conv1: q0 = inorm(bev_query + conv3x3(bev_query))
    convw_k<<<128, 256, 0, stream>>>(in_w, Wcv);
    chw2hwc_pad_k<<<256, 256, 0, stream>>>(bev_query, qT);
    bgemm_k<64, 0, 1, 1><<<dim3(1, 256), 256, 0, stream>>>(qT, Wcv, in_b, Bb, HW, 1152, 128);
    inorm_k<<<128, 256, 0, stream>>>(Bb, bev_query, Cb);

    // offsets, sample weights, pts, height (q0 in HWC bf16)
    chw2hwc_pad_k<<<256, 256, 0, stream>>>(Cb, qT);
    offsw_k<<<HW, 64, 0, stream>>>(qT, off_w, off_b, sw_w, sw_b, bev_pos, Dp, Eb, h_out);

    // PE: hidden (bf16) then MFMA GEMM into sf, in 2 row-chunks of 65536
    for (int ch = 0; ch < 2; ch++) {
        size_t row0 = (size_t)ch * 65536;
        pe_hidden_k<<<8192, 256, 0, stream>>>(Dp + row0 * 3, pe_w1, pe_b1, hb);
        bgemm_k<128, 0, 0, 0><<<dim3(1, 512), 256, 0, stream>>>(
            hb, Wpe, pe_b2, sfb + row0 * 128, 65536, 256, 128);
    }

    // sampling accumulates taps onto sf
    sample_k<<<HW, 128, 0, stream>>>(fT, Dp, Eb, l2i, sfb);

    // mid MLP (bf16 MFMA): 1024 -> 512 gelu -> 512 gelu -> 128 linear (CHW fp32)
    bgemm_k<128, 1, 0, 0><<<dim3(4, 128), 256, 0, stream>>>(sfb, Wb1, mid_b1, m1b, HW, 1024, 512);
    bgemm_k<128, 1, 0, 0><<<dim3(4, 128), 256, 0, stream>>>(m1b, Wb2, mid_b2, m2b, HW, 512, 512);
    bgemm_k<64, 0, 1, 0><<<dim3(1, 256), 256, 0, stream>>>(m2b, Wb3, mid_b3, Bb, HW, 512, 128);

    // q1 = inorm(q0 + m)
    inorm_k<<<128, 256, 0, stream>>>(Cb, Bb, Gb);

    // conv2: q = inorm(q1 + conv3x3(q1))
    convw_k<<<128, 256, 0, stream>>>(out_w, Wcv);
    chw2hwc_pad_k<<<256, 256, 0, stream>>>(Gb, qT);
    bgemm_k<64, 0, 1, 1><<<dim3(1, 256), 256, 0, stream>>>(qT, Wcv, out_b, Cb, HW, 1152, 128);
    inorm_k<<<128, 256, 0, stream>>>(Cb, Gb, q_out);
}

// Round 6
// 564.327 us; speedup vs baseline: 3.7292x; 1.0530x over previous
//
#include <hip/hip_runtime.h>
#include <hip/hip_bf16.h>
#include <math.h>

#define HW 16384   // 128*128 bev pixels

typedef __attribute__((ext_vector_type(8))) short short8;
typedef __attribute__((ext_vector_type(4))) float floatx4;
typedef __attribute__((ext_vector_type(2))) float floatx2;

__device__ __forceinline__ float gelu_exact(float x){
    return 0.5f * x * (1.0f + erff(x * 0.7071067811865475f));
}

__device__ __forceinline__ floatx2 bf2x(unsigned int u){
    floatx2 r;
    r.x = __uint_as_float(u << 16);
    r.y = __uint_as_float(u & 0xffff0000u);
    return r;
}

// ---------------- feat transpose: (N,C,H,W) fp32 -> (N,H,W,C) bf16 ----------------
__global__ __launch_bounds__(256) void feat_transpose_k(
    const float* __restrict__ in, __hip_bfloat16* __restrict__ out, int Hl, int Wl, int total)
{
    int idx = blockIdx.x * 256 + threadIdx.x;
    if (idx >= total) return;
    int c   = idx & 127;
    int pix = idx >> 7;
    int x   = pix % Wl;
    int tt  = pix / Wl;
    int y   = tt % Hl;
    int n   = tt / Hl;
    out[idx] = __float2bfloat16(in[((n * 128 + c) * Hl + y) * Wl + x]);
}

// ---------------- fp32 -> bf16 conversion ----------------
__global__ __launch_bounds__(256) void cvt_bf16_k(
    const float* __restrict__ in, __hip_bfloat16* __restrict__ out, int n)
{
    int i = blockIdx.x * 256 + threadIdx.x;
    if (i < n) out[i] = __float2bfloat16(in[i]);
}

// ---------------- pe_w2 [256][128] -> W[n][k] bf16 [128][256] ----------------
__global__ __launch_bounds__(256) void cvt_pew2T_k(
    const float* __restrict__ w, __hip_bfloat16* __restrict__ out)
{
    int n = blockIdx.x, k = threadIdx.x;
    out[n * 256 + k] = __float2bfloat16(w[k * 128 + n]);
}

// ---------------- conv weight rearrange: w[o][i][dy][dx] -> wre[o][(dy*3+dx)*128+i] bf16 ----------------
__global__ __launch_bounds__(256) void convw_k(
    const float* __restrict__ w, __hip_bfloat16* __restrict__ wre)
{
    int o = blockIdx.x;
    for (int idx = threadIdx.x; idx < 1152; idx += 256) {
        int s = idx >> 7, i = idx & 127;
        wre[o * 1152 + idx] = __float2bfloat16(w[(o * 128 + i) * 9 + s]);
    }
}

// ---------------- CHW fp32 [128][128^2] -> padded HWC bf16 [130][130][128] (interior) ----------------
__global__ __launch_bounds__(256) void chw2hwc_pad_k(
    const float* __restrict__ q, __hip_bfloat16* __restrict__ out)
{
    __shared__ float tile[128][65];
    int b = blockIdx.x;            // 256 blocks: y = b>>1, x0 = (b&1)*64
    int y = b >> 1, x0 = (b & 1) * 64;
    int t = threadIdx.x;
    int xi = t & 63, c0 = t >> 6;
    for (int c = c0; c < 128; c += 4)
        tile[c][xi] = q[c * HW + y * 128 + x0 + xi];
    __syncthreads();
    int xp = t >> 2, cg = (t & 3) * 32;
    __hip_bfloat16* dst = out + ((size_t)(y + 1) * 130 + (x0 + 1 + xp)) * 128;
    #pragma unroll
    for (int g = 0; g < 4; g++) {
        int c = cg + g * 8;
        union { __hip_bfloat16 h[8]; uint4 u; } pk;
        #pragma unroll
        for (int j = 0; j < 8; j++) pk.h[j] = __float2bfloat16(tile[c + j][xp]);
        *(uint4*)&dst[c] = pk.u;
    }
}

// ---------------- bf16 MFMA GEMM: out[m][n] = act(bias[n] + sum_k X[m][k] W[n][k]) ----------------
// BN = 128 fixed. OUTT: 0 -> bf16 [M][N]; 1 -> fp32 [N][M] (CHW).
// CONV: X is padded HWC bf16 [130][130][128]; k = s*128+c.
template<int BM, int ACT, int OUTT, int CONV>
__global__ __launch_bounds__(256) void bgemm_k(
    const __hip_bfloat16* __restrict__ X, const __hip_bfloat16* __restrict__ W,
    const float* __restrict__ bias, void* __restrict__ outp,
    int M, int K, int N)
{
    constexpr int ROWS = BM + 128;
    __shared__ __align__(16) __hip_bfloat16 SH[ROWS * 32];
    __hip_bfloat16* As = SH;
    __hip_bfloat16* Bs = SH + BM * 32;
    int t = threadIdx.x;
    int w = t >> 6, lane = t & 63;
    int mb = blockIdx.y * BM, nb = blockIdx.x * 128;
    int cy = mb >> 7, cx = mb & 127;   // conv tile coords (CONV only)
    constexpr int WM = BM / 2;
    constexpr int MI = WM / 16;
    int wm = (w & 1) * WM, wn = (w >> 1) * 64;
    int lm = lane & 15, lq = lane >> 4;
    floatx4 zero = {0.f, 0.f, 0.f, 0.f};
    floatx4 acc[MI][4];
    #pragma unroll
    for (int i = 0; i < MI; i++)
        #pragma unroll
        for (int j = 0; j < 4; j++) acc[i][j] = zero;
    constexpr int ITERS = (ROWS * 4) / 256;
    for (int kb = 0; kb < K; kb += 32) {
        int s = kb >> 7;
        int dyi = s / 3, dxi = s - dyi * 3;   // tap indices (CONV only)
        __syncthreads();
        #pragma unroll
        for (int it = 0; it < ITERS; it++) {
            int chunk = it * 256 + t;
            int row = chunk >> 2, ko = (chunk & 3) * 8;
            const __hip_bfloat16* src;
            if (row < BM) {
                if (CONV)
                    src = X + (((size_t)(cy + dyi) * 130) + (cx + dxi + row)) * 128 + (kb & 127) + ko;
                else
                    src = X + (size_t)(mb + row) * K + kb + ko;
            } else {
                src = W + (size_t)(nb + row - BM) * K + kb + ko;
            }
            // async global -> LDS, 16B/lane; dest = wave-uniform base + lane*16
            __builtin_amdgcn_global_load_lds(
                (const __attribute__((address_space(1))) void*)src,
                (__attribute__((address_space(3))) void*)&SH[(size_t)(it * 256 + (t & ~63)) * 8],
                16, 0, 0);
        }
        __syncthreads();   // drains vmcnt -> LDS visible
        short8 af[MI], bf[4];
        #pragma unroll
        for (int i = 0; i < MI; i++)
            af[i] = *(const short8*)&As[(wm + i * 16 + lm) * 32 + lq * 8];
        #pragma unroll
        for (int j = 0; j < 4; j++)
            bf[j] = *(const short8*)&Bs[(wn + j * 16 + lm) * 32 + lq * 8];
        #pragma unroll
        for (int i = 0; i < MI; i++)
            #pragma unroll
            for (int j = 0; j < 4; j++)
                acc[i][j] = __builtin_amdgcn_mfma_f32_16x16x32_bf16(af[i], bf[j], acc[i][j], 0, 0, 0);
    }
    #pragma unroll
    for (int i = 0; i < MI; i++) {
        #pragma unroll
        for (int j = 0; j < 4; j++) {
            int n = nb + wn + j * 16 + lm;
            float bv = bias[n];
            #pragma unroll
            for (int r = 0; r < 4; r++) {
                int m = mb + wm + i * 16 + lq * 4 + r;
                float v = acc[i][j][r] + bv;
                if (ACT) v = gelu_exact(v);
                if (OUTT == 0) ((__hip_bfloat16*)outp)[(size_t)m * N + n] = __float2bfloat16(v);
                else           ((float*)outp)[(size_t)n * M + m] = v;
            }
        }
    }
}

// ---------------- instance norm (optionally a+b) over HW per channel ----------------
__global__ __launch_bounds__(256) void inorm_k(
    const float* __restrict__ a, const float* __restrict__ addc, float* __restrict__ out)
{
    int c = blockIdx.x;
    const float* pa = a + (size_t)c * HW;
    const float* pb = addc ? addc + (size_t)c * HW : nullptr;
    const bool hasb = (pb != nullptr);
    float s = 0.f, s2 = 0.f;
    for (int i = threadIdx.x; i < HW; i += 256) {
        float v = hasb ? (pa[i] + pb[i]) : pa[i];
        s += v; s2 += v * v;
    }
    #pragma unroll
    for (int off = 32; off > 0; off >>= 1) {
        s  += __shfl_down(s,  off);
        s2 += __shfl_down(s2, off);
    }
    __shared__ float ls[4], ls2[4], stats[2];
    int wid = threadIdx.x >> 6, lane = threadIdx.x & 63;
    if (lane == 0) { ls[wid] = s; ls2[wid] = s2; }
    __syncthreads();
    if (threadIdx.x == 0) {
        float t = 0.f, t2 = 0.f;
        for (int i = 0; i < 4; i++) { t += ls[i]; t2 += ls2[i]; }
        float mean = t * (1.0f / HW);
        float var  = t2 * (1.0f / HW) - mean * mean;
        stats[0] = mean;
        stats[1] = rsqrtf(var + 1e-5f);
    }
    __syncthreads();
    float mean = stats[0], rstd = stats[1];
    float* po = out + (size_t)c * HW;
    for (int i = threadIdx.x; i < HW; i += 256) {
        float v = hasb ? (pa[i] + pb[i]) : pa[i];
        po[i] = (v - mean) * rstd;
    }
}

// ---------------- offsets + sample-weights per pixel (reads padded HWC bf16 q0) ----------------
__global__ __launch_bounds__(64) void offsw_k(
    const __hip_bfloat16* __restrict__ qT,
    const float* __restrict__ off_w, const float* __restrict__ off_b,
    const float* __restrict__ sw_w,  const float* __restrict__ sw_b,
    const float* __restrict__ bev_pos,
    float* __restrict__ pts, float* __restrict__ swn, float* __restrict__ height_out)
{
    int pix = blockIdx.x;
    int t = threadIdx.x;
    __shared__ float qv[128];
    __shared__ float raw[32];
    int y = pix >> 7, x = pix & 127;
    const __hip_bfloat16* qrow = qT + ((size_t)(y + 1) * 130 + (x + 1)) * 128;
    qv[t]      = __bfloat162float(qrow[t]);
    qv[t + 64] = __bfloat162float(qrow[t + 64]);
    __syncthreads();
    if (t < 24) {
        const float* wr = off_w + t * 128;
        float acc = off_b[t];
        for (int k = 0; k < 128; k++) acc += wr[k] * qv[k];
        float sv = 1.f / (1.f + expf(-acc));
        int p = t / 3, d = t - p * 3;
        float lim = (d == 2) ? (4.0f + 1e-6f) : (0.25f + 1e-6f);
        float offv = sv * 2.f * lim - lim;
        const float pcmin[3] = {-50.f, -50.f, -4.f};
        const float rng[3]   = {100.f, 100.f, 8.f};
        float refv = bev_pos[pix * 3 + d] * rng[d] + pcmin[d];
        pts[(pix * 8 + p) * 3 + d] = refv + offv;
        if (d == 2) height_out[p * HW + pix] = offv;
    } else if (t < 56) {
        int r = t - 24;
        const float* wr = sw_w + r * 128;
        float acc = sw_b[r];
        for (int k = 0; k < 128; k++) acc += wr[k] * qv[k];
        raw[r] = acc;
    }
    __syncthreads();
    if (t < 8) {
        float m = raw[t * 4];
        #pragma unroll
        for (int l = 1; l < 4; l++) m = fmaxf(m, raw[t * 4 + l]);
        float e[4], sum = 0.f;
        #pragma unroll
        for (int l = 0; l < 4; l++) { e[l] = expf(raw[t * 4 + l] - m); sum += e[l]; }
        float inv = 1.f / sum;
        #pragma unroll
        for (int l = 0; l < 4; l++) swn[(pix * 8 + t) * 4 + l] = e[l] * inv;
    }
}

// ---------------- PE hidden layer: h[row][256] bf16 ----------------
__global__ __launch_bounds__(256) void pe_hidden_k(
    const float* __restrict__ pts, const float* __restrict__ pe_w1,
    const float* __restrict__ pe_b1, __hip_bfloat16* __restrict__ h)
{
    __shared__ float w1s[768];
    __shared__ float b1s[256];
    int t = threadIdx.x;
    for (int i = t; i < 768; i += 256) w1s[i] = pe_w1[i];
    b1s[t] = pe_b1[t];
    __syncthreads();
    int r = t >> 5, jg = (t & 31) * 8;
    size_t row = (size_t)blockIdx.x * 8 + r;
    float rn0 = (pts[row * 3 + 0] + 50.f) * 0.01f;
    float rn1 = (pts[row * 3 + 1] + 50.f) * 0.01f;
    float rn2 = (pts[row * 3 + 2] + 4.f) * 0.125f;
    union { __hip_bfloat16 hh[8]; uint4 u; } pk;
    #pragma unroll
    for (int j = 0; j < 8; j++) {
        int jj = jg + j;
        float v = b1s[jj] + rn0 * w1s[jj] + rn1 * w1s[256 + jj] + rn2 * w1s[512 + jj];
        pk.hh[j] = __float2bfloat16(fmaxf(v, 0.f));
    }
    *(uint4*)&h[row * 256 + jg] = pk.u;
}

// ---------------- sampling: phase-1 per-combo projection + cull, phase-2 packed gather ----------------
// 128 threads = 2 waves; wave wv handles p = wv*4+i, lane owns channel pair c = 2*lane.
__global__ __launch_bounds__(128) void sample_k(
    const __hip_bfloat16* __restrict__ featT, const float* __restrict__ pts,
    const float* __restrict__ swn,   const float* __restrict__ l2i,
    __hip_bfloat16* __restrict__ sf)
{
    int pix = blockIdx.x;
    int t = threadIdx.x;
    int lane = t & 63, wv = t >> 6;
    __shared__ float pts_s[24];
    __shared__ float swl_s[32];
    __shared__ float M[96];
    __shared__ __align__(16) int   offs[8][24][4];
    __shared__ __align__(16) float wts[8][24][4];
    __shared__ int cnt[8];
    if (t < 96) M[t] = l2i[t];
    if (t < 24) pts_s[t] = pts[pix * 24 + t];
    if (t < 32) swl_s[t] = swn[pix * 32 + t];
    if (t < 8)  cnt[t] = 0;
    __syncthreads();

    // preload PE rows (packed)
    floatx2 acc[4];
    #pragma unroll
    for (int i = 0; i < 4; i++) {
        unsigned int u = *(const unsigned int*)&sf[(size_t)pix * 1024 + (wv * 4 + i) * 128 + 2 * lane];
        acc[i] = bf2x(u);
    }

    const int lHt[4] = {32, 16, 8, 4}, lWt[4] = {88, 44, 22, 11};
    const int loff[4] = {0, 2162688, 2703360, 2838528};
    // phase 1: 192 combos across 128 threads
    for (int cb = t; cb < 192; cb += 128) {
        int p = cb / 24;
        int rr = cb - p * 24;
        int n = rr >> 2, l = rr & 3;
        float X = pts_s[p * 3], Y = pts_s[p * 3 + 1], Z = pts_s[p * 3 + 2];
        const float* Mn = &M[n * 16];
        float zc = Mn[8] * X + Mn[9] * Y + Mn[10] * Z + Mn[11];
        if (zc > 1e-5f) {
            float inv = 1.f / zc;
            float xn = (Mn[0] * X + Mn[1] * Y + Mn[2] * Z + Mn[3]) * inv * (1.f / 704.f);
            float yn = (Mn[4] * X + Mn[5] * Y + Mn[6] * Z + Mn[7]) * inv * (1.f / 256.f);
            int Wl = lWt[l], Hl = lHt[l];
            float px = xn * Wl - 0.5f, py = yn * Hl - 0.5f;
            px = fminf(fmaxf(px, -2.f), (float)(Wl + 1));
            py = fminf(fmaxf(py, -2.f), (float)(Hl + 1));
            float x0f = floorf(px), y0f = floorf(py);
            float wx = px - x0f, wy = py - y0f;
            int x0 = (int)x0f, y0 = (int)y0f;
            bool xi0 = (unsigned)x0 < (unsigned)Wl, xi1 = (unsigned)(x0 + 1) < (unsigned)Wl;
            bool yi0 = (unsigned)y0 < (unsigned)Hl, yi1 = (unsigned)(y0 + 1) < (unsigned)Hl;
            if ((xi0 || xi1) && (yi0 || yi1)) {
                float wl = swl_s[p * 4 + l];
                float w00 = wl * (1.f - wx) * (1.f - wy) * (float)(xi0 && yi0);
                float w10 = wl * wx * (1.f - wy)         * (float)(xi1 && yi0);
                float w01 = wl * (1.f - wx) * wy         * (float)(xi0 && yi1);
                float w11 = wl * wx * wy                 * (float)(xi1 && yi1);
                int x0c = min(max(x0, 0), Wl - 1), x1c = min(max(x0 + 1, 0), Wl - 1);
                int y0c = min(max(y0, 0), Hl - 1), y1c = min(max(y0 + 1, 0), Hl - 1);
                int base = loff[l] + n * Hl * Wl * 128;
                int idx = atomicAdd(&cnt[p], 1);
                offs[p][idx][0] = base + (y0c * Wl + x0c) * 128;
                offs[p][idx][1] = base + (y0c * Wl + x1c) * 128;
                offs[p][idx][2] = base + (y1c * Wl + x0c) * 128;
                offs[p][idx][3] = base + (y1c * Wl + x1c) * 128;
                wts[p][idx][0] = w00; wts[p][idx][1] = w10;
                wts[p][idx][2] = w01; wts[p][idx][3] = w11;
            }
        }
    }
    __syncthreads();

    // phase 2: packed gather — wave wv covers p = wv*4 .. wv*4+3
    #pragma unroll 1
    for (int i = 0; i < 4; i++) {
        int p = wv * 4 + i;
        int np = cnt[p];
        floatx2 a = acc[i];
        #pragma unroll 1
        for (int j = 0; j < np; j++) {
            int4   o = *(const int4*)&offs[p][j][0];
            float4 w = *(const float4*)&wts[p][j][0];
            unsigned int v0 = ((const unsigned int*)(featT + o.x))[lane];
            unsigned int v1 = ((const unsigned int*)(featT + o.y))[lane];
            unsigned int v2 = ((const unsigned int*)(featT + o.z))[lane];
            unsigned int v3 = ((const unsigned int*)(featT + o.w))[lane];
            a += bf2x(v0) * w.x;
            a += bf2x(v1) * w.y;
            a += bf2x(v2) * w.z;
            a += bf2x(v3) * w.w;
        }
        acc[i] = a;
    }
    #pragma unroll
    for (int i = 0; i < 4; i++) {
        union { __hip_bfloat16 h[2]; unsigned int u; } pk;
        pk.h[0] = __float2bfloat16(acc[i].x);
        pk.h[1] = __float2bfloat16(acc[i].y);
        *(unsigned int*)&sf[(size_t)pix * 1024 + (wv * 4 + i) * 128 + 2 * lane] = pk.u;
    }
}

extern "C" void kernel_launch(void* const* d_in, const int* in_sizes, int n_in,
                              void* d_out, int out_size, void* d_ws, size_t ws_size,
                              hipStream_t stream)
{
    const float* feat[4] = {(const float*)d_in[0], (const float*)d_in[1],
                            (const float*)d_in[2], (const float*)d_in[3]};
    const float* l2i       = (const float*)d_in[4];
    const float* bev_query = (const float*)d_in[5];
    const float* bev_pos   = (const float*)d_in[6];
    const float* in_w  = (const float*)d_in[7];  const float* in_b  = (const float*)d_in[8];
    const float* off_w = (const float*)d_in[9];  const float* off_b = (const float*)d_in[10];
    const float* sw_w  = (const float*)d_in[11]; const float* sw_b  = (const float*)d_in[12];
    const float* pe_w1 = (const float*)d_in[13]; const float* pe_b1 = (const float*)d_in[14];
    const float* pe_w2 = (const float*)d_in[15]; const float* pe_b2 = (const float*)d_in[16];
    const float* mid_w1 = (const float*)d_in[17]; const float* mid_b1 = (const float*)d_in[18];
    const float* mid_w2 = (const float*)d_in[19]; const float* mid_b2 = (const float*)d_in[20];
    const float* mid_w3 = (const float*)d_in[21]; const float* mid_b3 = (const float*)d_in[22];
    const float* out_w  = (const float*)d_in[23]; const float* out_b  = (const float*)d_in[24];

    float* ws = (float*)d_ws;
    // workspace layout (floats), total 27,020,032 fl = 108.1 MB
    float* fTf = ws;                    // 1,436,160 : transposed feats bf16 (2,872,320 elems)
    __hip_bfloat16* fT = (__hip_bfloat16*)fTf;
    float* Bb  = fTf + 1436160;         // 2,097,152 : conv out / m3 (CHW)
    float* Cb  = Bb + 2097152;          // 2,097,152 : q0 / conv2 out
    float* Gb  = Cb + 2097152;          // 2,097,152 : q1 (CHW)
    float* Dp  = Gb + 2097152;          //   393,216 : pts
    float* Eb  = Dp + 393216;           //   524,288 : swn
    float* QTf = Eb + 524288;           // 1,081,600 : padded HWC bf16 (130*130*128), serial reuse
    __hip_bfloat16* qT = (__hip_bfloat16*)QTf;
    float* SFf = QTf + 1081600;         // 8,388,608 : sf bf16 131072x128
    __hip_bfloat16* sfb = (__hip_bfloat16*)SFf;
    float* M1f = SFf + 8388608;         // 4,194,304 : m1 bf16 | (with M2f) chunked PE hidden
    __hip_bfloat16* m1b = (__hip_bfloat16*)M1f;
    __hip_bfloat16* hb  = (__hip_bfloat16*)M1f;     // 65536 x 256 bf16 (M1f+M2f)
    float* M2f = M1f + 4194304;         // 4,194,304 : m2 bf16
    __hip_bfloat16* m2b = (__hip_bfloat16*)M2f;
    float* Wc  = M2f + 4194304;         //    73,728 : conv weights bf16
    __hip_bfloat16* Wcv = (__hip_bfloat16*)Wc;
    float* W1f = Wc + 73728;            //   262,144
    __hip_bfloat16* Wb1 = (__hip_bfloat16*)W1f;
    float* W2f = W1f + 262144;          //   131,072
    __hip_bfloat16* Wb2 = (__hip_bfloat16*)W2f;
    float* W3f = W2f + 131072;          //    32,768
    __hip_bfloat16* Wb3 = (__hip_bfloat16*)W3f;
    float* WPf = W3f + 32768;           //    16,384 : pe_w2^T bf16
    __hip_bfloat16* Wpe = (__hip_bfloat16*)WPf;

    float* q_out = (float*)d_out;
    float* h_out = q_out + 2097152;

    // zero padded HWC buffer border once (interior overwritten by each fill)
    hipMemsetAsync(qT, 0, (size_t)130 * 130 * 128 * sizeof(__hip_bfloat16), stream);

    const int lH[4] = {32, 16, 8, 4}, lW[4] = {88, 44, 22, 11};
    const int loff[4] = {0, 2162688, 2703360, 2838528};
    for (int l = 0; l < 4; l++) {
        int total = 6 * lH[l] * lW[l] * 128;
        feat_transpose_k<<<(total + 255) / 256, 256, 0, stream>>>(feat[l], fT + loff[l], lH[l], lW[l], total);
    }
    // weight prep
    cvt_bf16_k<<<(524288 + 255) / 256, 256, 0, stream>>>(mid_w1, Wb1, 524288);
    cvt_bf16_k<<<(262144 + 255) / 256, 256, 0, stream>>>(mid_w2, Wb2, 262144);
    cvt_bf16_k<<<(65536  + 255) / 256, 256, 0, stream>>>(mid_w3, Wb3, 65536);
    cvt_pew2T_k<<<128, 256, 0, stream>>>(pe_w2, Wpe);

    // conv1: q0 = inorm(bev_query + conv3x3(bev_query))
    convw_k<<<128, 256, 0, stream>>>(in_w, Wcv);
    chw2hwc_pad_k<<<256, 256, 0, stream>>>(bev_query, qT);
    bgemm_k<64, 0, 1, 1><<<dim3(1, 256), 256, 0, stream>>>(qT, Wcv, in_b, Bb, HW, 1152, 128);
    inorm_k<<<128, 256, 0, stream>>>(Bb, bev_query, Cb);

    // offsets, sample weights, pts, height (q0 in HWC bf16)
    chw2hwc_pad_k<<<256, 256, 0, stream>>>(Cb, qT);
    offsw_k<<<HW, 64, 0, stream>>>(qT, off_w, off_b, sw_w, sw_b, bev_pos, Dp, Eb, h_out);

    // PE: hidden (bf16) then MFMA GEMM into sf, in 2 row-chunks of 65536
    for (int ch = 0; ch < 2; ch++) {
        size_t row0 = (size_t)ch * 65536;
        pe_hidden_k<<<8192, 256, 0, stream>>>(Dp + row0 * 3, pe_w1, pe_b1, hb);
        bgemm_k<128, 0, 0, 0><<<dim3(1, 512), 256, 0, stream>>>(
            hb, Wpe, pe_b2, sfb + row0 * 128, 65536, 256, 128);
    }

    // sampling accumulates taps onto sf
    sample_k<<<HW, 128, 0, stream>>>(fT, Dp, Eb, l2i, sfb);

    // mid MLP (bf16 MFMA): 1024 -> 512 gelu -> 512 gelu -> 128 linear (CHW fp32)
    bgemm_k<128, 1, 0, 0><<<dim3(4, 128), 256, 0, stream>>>(sfb, Wb1, mid_b1, m1b, HW, 1024, 512);
    bgemm_k<128, 1, 0, 0><<<dim3(4, 128), 256, 0, stream>>>(m1b, Wb2, mid_b2, m2b, HW, 512, 512);
    bgemm_k<64, 0, 1, 0><<<dim3(1, 256), 256, 0, stream>>>(m2b, Wb3, mid_b3, Bb, HW, 512, 128);

    // q1 = inorm(q0 + m)
    inorm_k<<<128, 256, 0, stream>>>(Cb, Bb, Gb);

    // conv2: q = inorm(q1 + conv3x3(q1))
    convw_k<<<128, 256, 0, stream>>>(out_w, Wcv);
    chw2hwc_pad_k<<<256, 256, 0, stream>>>(Gb, qT);
    bgemm_k<64, 0, 1, 1><<<dim3(1, 256), 256, 0, stream>>>(qT, Wcv, out_b, Cb, HW, 1152, 128);
    inorm_k<<<128, 256, 0, stream>>>(Cb, Gb, q_out);
}

// Round 7
// 518.135 us; speedup vs baseline: 4.0617x; 1.0892x over previous
//
#include <hip/hip_runtime.h>
#include <hip/hip_bf16.h>
#include <math.h>

#define HW 16384   // 128*128 bev pixels

typedef __attribute__((ext_vector_type(8))) short short8;
typedef __attribute__((ext_vector_type(4))) float floatx4;
typedef __attribute__((ext_vector_type(2))) float floatx2;

__device__ __forceinline__ float gelu_exact(float x){
    return 0.5f * x * (1.0f + erff(x * 0.7071067811865475f));
}

__device__ __forceinline__ floatx2 bf2x(unsigned int u){
    floatx2 r;
    r.x = __uint_as_float(u << 16);
    r.y = __uint_as_float(u & 0xffff0000u);
    return r;
}

// ---------------- feat transpose: (N,C,H,W) fp32 -> (N,H,W,C) bf16 ----------------
__global__ __launch_bounds__(256) void feat_transpose_k(
    const float* __restrict__ in, __hip_bfloat16* __restrict__ out, int Hl, int Wl, int total)
{
    int idx = blockIdx.x * 256 + threadIdx.x;
    if (idx >= total) return;
    int c   = idx & 127;
    int pix = idx >> 7;
    int x   = pix % Wl;
    int tt  = pix / Wl;
    int y   = tt % Hl;
    int n   = tt / Hl;
    out[idx] = __float2bfloat16(in[((n * 128 + c) * Hl + y) * Wl + x]);
}

// ---------------- fp32 -> bf16 conversion ----------------
__global__ __launch_bounds__(256) void cvt_bf16_k(
    const float* __restrict__ in, __hip_bfloat16* __restrict__ out, int n)
{
    int i = blockIdx.x * 256 + threadIdx.x;
    if (i < n) out[i] = __float2bfloat16(in[i]);
}

// ---------------- pe_w2 [256][128] -> W[n][k] bf16 [128][256] ----------------
__global__ __launch_bounds__(256) void cvt_pew2T_k(
    const float* __restrict__ w, __hip_bfloat16* __restrict__ out)
{
    int n = blockIdx.x, k = threadIdx.x;
    out[n * 256 + k] = __float2bfloat16(w[k * 128 + n]);
}

// ---------------- conv weight rearrange: w[o][i][dy][dx] -> wre[o][(dy*3+dx)*128+i] bf16 ----------------
__global__ __launch_bounds__(256) void convw_k(
    const float* __restrict__ w, __hip_bfloat16* __restrict__ wre)
{
    int o = blockIdx.x;
    for (int idx = threadIdx.x; idx < 1152; idx += 256) {
        int s = idx >> 7, i = idx & 127;
        wre[o * 1152 + idx] = __float2bfloat16(w[(o * 128 + i) * 9 + s]);
    }
}

// ---------------- pack off_w(24)+sw_w(32) rows -> [128][128] bf16 + bias fp32[128] ----------------
__global__ __launch_bounds__(128) void offsw_prep_k(
    const float* __restrict__ off_w, const float* __restrict__ off_b,
    const float* __restrict__ sw_w,  const float* __restrict__ sw_b,
    __hip_bfloat16* __restrict__ Wc, float* __restrict__ bc)
{
    int n = blockIdx.x, k = threadIdx.x;
    float w = 0.f;
    if (n < 24)      w = off_w[n * 128 + k];
    else if (n < 56) w = sw_w[(n - 24) * 128 + k];
    Wc[n * 128 + k] = __float2bfloat16(w);
    if (k == 0) bc[n] = (n < 24) ? off_b[n] : ((n < 56) ? sw_b[n - 24] : 0.f);
}

// ---------------- CHW fp32 [128][128^2] -> padded HWC bf16 [130][130][128] (interior) ----------------
__global__ __launch_bounds__(256) void chw2hwc_pad_k(
    const float* __restrict__ q, __hip_bfloat16* __restrict__ out)
{
    __shared__ float tile[128][65];
    int b = blockIdx.x;            // 256 blocks: y = b>>1, x0 = (b&1)*64
    int y = b >> 1, x0 = (b & 1) * 64;
    int t = threadIdx.x;
    int xi = t & 63, c0 = t >> 6;
    for (int c = c0; c < 128; c += 4)
        tile[c][xi] = q[c * HW + y * 128 + x0 + xi];
    __syncthreads();
    int xp = t >> 2, cg = (t & 3) * 32;
    __hip_bfloat16* dst = out + ((size_t)(y + 1) * 130 + (x0 + 1 + xp)) * 128;
    #pragma unroll
    for (int g = 0; g < 4; g++) {
        int c = cg + g * 8;
        union { __hip_bfloat16 h[8]; uint4 u; } pk;
        #pragma unroll
        for (int j = 0; j < 8; j++) pk.h[j] = __float2bfloat16(tile[c + j][xp]);
        *(uint4*)&dst[c] = pk.u;
    }
}

// ---------------- bf16 MFMA GEMM: out[m][n] = act(bias[n] + sum_k X[m][k] W[n][k]) ----------------
// BN = 128 fixed. OUTT: 0 -> bf16 [M][N]; 1 -> fp32 [N][M] (CHW).
// CONV: X is padded HWC bf16 [130][130][128]; k = s*128+c.
template<int BM, int ACT, int OUTT, int CONV>
__global__ __launch_bounds__(256) void bgemm_k(
    const __hip_bfloat16* __restrict__ X, const __hip_bfloat16* __restrict__ W,
    const float* __restrict__ bias, void* __restrict__ outp,
    int M, int K, int N)
{
    constexpr int ROWS = BM + 128;
    __shared__ __align__(16) __hip_bfloat16 SH[ROWS * 32];
    __hip_bfloat16* As = SH;
    __hip_bfloat16* Bs = SH + BM * 32;
    int t = threadIdx.x;
    int w = t >> 6, lane = t & 63;
    int mb = blockIdx.y * BM, nb = blockIdx.x * 128;
    int cy = mb >> 7, cx = mb & 127;   // conv tile coords (CONV only)
    constexpr int WM = BM / 2;
    constexpr int MI = WM / 16;
    int wm = (w & 1) * WM, wn = (w >> 1) * 64;
    int lm = lane & 15, lq = lane >> 4;
    floatx4 zero = {0.f, 0.f, 0.f, 0.f};
    floatx4 acc[MI][4];
    #pragma unroll
    for (int i = 0; i < MI; i++)
        #pragma unroll
        for (int j = 0; j < 4; j++) acc[i][j] = zero;
    constexpr int ITERS = (ROWS * 4) / 256;
    for (int kb = 0; kb < K; kb += 32) {
        int s = kb >> 7;
        int dyi = s / 3, dxi = s - dyi * 3;   // tap indices (CONV only)
        __syncthreads();
        #pragma unroll
        for (int it = 0; it < ITERS; it++) {
            int chunk = it * 256 + t;
            int row = chunk >> 2, ko = (chunk & 3) * 8;
            const __hip_bfloat16* src;
            if (row < BM) {
                if (CONV)
                    src = X + (((size_t)(cy + dyi) * 130) + (cx + dxi + row)) * 128 + (kb & 127) + ko;
                else
                    src = X + (size_t)(mb + row) * K + kb + ko;
            } else {
                src = W + (size_t)(nb + row - BM) * K + kb + ko;
            }
            // async global -> LDS, 16B/lane; dest = wave-uniform base + lane*16
            __builtin_amdgcn_global_load_lds(
                (const __attribute__((address_space(1))) void*)src,
                (__attribute__((address_space(3))) void*)&SH[(size_t)(it * 256 + (t & ~63)) * 8],
                16, 0, 0);
        }
        __syncthreads();   // drains vmcnt -> LDS visible
        short8 af[MI], bf[4];
        #pragma unroll
        for (int i = 0; i < MI; i++)
            af[i] = *(const short8*)&As[(wm + i * 16 + lm) * 32 + lq * 8];
        #pragma unroll
        for (int j = 0; j < 4; j++)
            bf[j] = *(const short8*)&Bs[(wn + j * 16 + lm) * 32 + lq * 8];
        #pragma unroll
        for (int i = 0; i < MI; i++)
            #pragma unroll
            for (int j = 0; j < 4; j++)
                acc[i][j] = __builtin_amdgcn_mfma_f32_16x16x32_bf16(af[i], bf[j], acc[i][j], 0, 0, 0);
    }
    #pragma unroll
    for (int i = 0; i < MI; i++) {
        #pragma unroll
        for (int j = 0; j < 4; j++) {
            int n = nb + wn + j * 16 + lm;
            float bv = bias[n];
            #pragma unroll
            for (int r = 0; r < 4; r++) {
                int m = mb + wm + i * 16 + lq * 4 + r;
                float v = acc[i][j][r] + bv;
                if (ACT) v = gelu_exact(v);
                if (OUTT == 0) ((__hip_bfloat16*)outp)[(size_t)m * N + n] = __float2bfloat16(v);
                else           ((float*)outp)[(size_t)n * M + m] = v;
            }
        }
    }
}

// ---------------- instance norm (optionally a+b) over HW per channel ----------------
__global__ __launch_bounds__(256) void inorm_k(
    const float* __restrict__ a, const float* __restrict__ addc, float* __restrict__ out)
{
    int c = blockIdx.x;
    const float* pa = a + (size_t)c * HW;
    const float* pb = addc ? addc + (size_t)c * HW : nullptr;
    const bool hasb = (pb != nullptr);
    float s = 0.f, s2 = 0.f;
    for (int i = threadIdx.x; i < HW; i += 256) {
        float v = hasb ? (pa[i] + pb[i]) : pa[i];
        s += v; s2 += v * v;
    }
    #pragma unroll
    for (int off = 32; off > 0; off >>= 1) {
        s  += __shfl_down(s,  off);
        s2 += __shfl_down(s2, off);
    }
    __shared__ float ls[4], ls2[4], stats[2];
    int wid = threadIdx.x >> 6, lane = threadIdx.x & 63;
    if (lane == 0) { ls[wid] = s; ls2[wid] = s2; }
    __syncthreads();
    if (threadIdx.x == 0) {
        float t = 0.f, t2 = 0.f;
        for (int i = 0; i < 4; i++) { t += ls[i]; t2 += ls2[i]; }
        float mean = t * (1.0f / HW);
        float var  = t2 * (1.0f / HW) - mean * mean;
        stats[0] = mean;
        stats[1] = rsqrtf(var + 1e-5f);
    }
    __syncthreads();
    float mean = stats[0], rstd = stats[1];
    float* po = out + (size_t)c * HW;
    for (int i = threadIdx.x; i < HW; i += 256) {
        float v = hasb ? (pa[i] + pb[i]) : pa[i];
        po[i] = (v - mean) * rstd;
    }
}

// ---------------- offsw epilogue: raw [n][16384] fp32 -> pts/swn/height ----------------
__global__ __launch_bounds__(256) void offpost_k(
    const float* __restrict__ raw, const float* __restrict__ bev_pos,
    float* __restrict__ pts, float* __restrict__ swn, float* __restrict__ height_out)
{
    int pix = blockIdx.x * 256 + threadIdx.x;
    const float pcmin[3] = {-50.f, -50.f, -4.f};
    const float rng[3]   = {100.f, 100.f, 8.f};
    float bp[3];
    #pragma unroll
    for (int d = 0; d < 3; d++) bp[d] = bev_pos[pix * 3 + d];
    #pragma unroll
    for (int p = 0; p < 8; p++) {
        #pragma unroll
        for (int d = 0; d < 3; d++) {
            float acc = raw[(p * 3 + d) * HW + pix];
            float sv = 1.f / (1.f + expf(-acc));
            float lim = (d == 2) ? (4.0f + 1e-6f) : (0.25f + 1e-6f);
            float offv = sv * 2.f * lim - lim;
            float refv = bp[d] * rng[d] + pcmin[d];
            pts[pix * 24 + p * 3 + d] = refv + offv;
            if (d == 2) height_out[p * HW + pix] = offv;
        }
        float r[4], m = -1e30f;
        #pragma unroll
        for (int l = 0; l < 4; l++) {
            r[l] = raw[(24 + p * 4 + l) * HW + pix];
            m = fmaxf(m, r[l]);
        }
        float sum = 0.f;
        #pragma unroll
        for (int l = 0; l < 4; l++) { r[l] = expf(r[l] - m); sum += r[l]; }
        float inv = 1.f / sum;
        #pragma unroll
        for (int l = 0; l < 4; l++) swn[pix * 32 + p * 4 + l] = r[l] * inv;
    }
}

// ---------------- PE hidden layer: h[row][256] bf16 ----------------
__global__ __launch_bounds__(256) void pe_hidden_k(
    const float* __restrict__ pts, const float* __restrict__ pe_w1,
    const float* __restrict__ pe_b1, __hip_bfloat16* __restrict__ h)
{
    __shared__ float w1s[768];
    __shared__ float b1s[256];
    int t = threadIdx.x;
    for (int i = t; i < 768; i += 256) w1s[i] = pe_w1[i];
    b1s[t] = pe_b1[t];
    __syncthreads();
    int r = t >> 5, jg = (t & 31) * 8;
    size_t row = (size_t)blockIdx.x * 8 + r;
    float rn0 = (pts[row * 3 + 0] + 50.f) * 0.01f;
    float rn1 = (pts[row * 3 + 1] + 50.f) * 0.01f;
    float rn2 = (pts[row * 3 + 2] + 4.f) * 0.125f;
    union { __hip_bfloat16 hh[8]; uint4 u; } pk;
    #pragma unroll
    for (int j = 0; j < 8; j++) {
        int jj = jg + j;
        float v = b1s[jj] + rn0 * w1s[jj] + rn1 * w1s[256 + jj] + rn2 * w1s[512 + jj];
        pk.hh[j] = __float2bfloat16(fmaxf(v, 0.f));
    }
    *(uint4*)&h[row * 256 + jg] = pk.u;
}

// ---------------- sampling: phase-1 per-combo projection + cull, phase-2 packed gather ----------------
__global__ __launch_bounds__(128) void sample_k(
    const __hip_bfloat16* __restrict__ featT, const float* __restrict__ pts,
    const float* __restrict__ swn,   const float* __restrict__ l2i,
    __hip_bfloat16* __restrict__ sf)
{
    int pix = blockIdx.x;
    int t = threadIdx.x;
    int lane = t & 63, wv = t >> 6;
    __shared__ float pts_s[24];
    __shared__ float swl_s[32];
    __shared__ float M[96];
    __shared__ __align__(16) int   offs[8][24][4];
    __shared__ __align__(16) float wts[8][24][4];
    __shared__ int cnt[8];
    if (t < 96) M[t] = l2i[t];
    if (t < 24) pts_s[t] = pts[pix * 24 + t];
    if (t < 32) swl_s[t] = swn[pix * 32 + t];
    if (t < 8)  cnt[t] = 0;
    __syncthreads();

    floatx2 acc[4];
    #pragma unroll
    for (int i = 0; i < 4; i++) {
        unsigned int u = *(const unsigned int*)&sf[(size_t)pix * 1024 + (wv * 4 + i) * 128 + 2 * lane];
        acc[i] = bf2x(u);
    }

    const int lHt[4] = {32, 16, 8, 4}, lWt[4] = {88, 44, 22, 11};
    const int loff[4] = {0, 2162688, 2703360, 2838528};
    for (int cb = t; cb < 192; cb += 128) {
        int p = cb / 24;
        int rr = cb - p * 24;
        int n = rr >> 2, l = rr & 3;
        float X = pts_s[p * 3], Y = pts_s[p * 3 + 1], Z = pts_s[p * 3 + 2];
        const float* Mn = &M[n * 16];
        float zc = Mn[8] * X + Mn[9] * Y + Mn[10] * Z + Mn[11];
        if (zc > 1e-5f) {
            float inv = 1.f / zc;
            float xn = (Mn[0] * X + Mn[1] * Y + Mn[2] * Z + Mn[3]) * inv * (1.f / 704.f);
            float yn = (Mn[4] * X + Mn[5] * Y + Mn[6] * Z + Mn[7]) * inv * (1.f / 256.f);
            int Wl = lWt[l], Hl = lHt[l];
            float px = xn * Wl - 0.5f, py = yn * Hl - 0.5f;
            px = fminf(fmaxf(px, -2.f), (float)(Wl + 1));
            py = fminf(fmaxf(py, -2.f), (float)(Hl + 1));
            float x0f = floorf(px), y0f = floorf(py);
            float wx = px - x0f, wy = py - y0f;
            int x0 = (int)x0f, y0 = (int)y0f;
            bool xi0 = (unsigned)x0 < (unsigned)Wl, xi1 = (unsigned)(x0 + 1) < (unsigned)Wl;
            bool yi0 = (unsigned)y0 < (unsigned)Hl, yi1 = (unsigned)(y0 + 1) < (unsigned)Hl;
            if ((xi0 || xi1) && (yi0 || yi1)) {
                float wl = swl_s[p * 4 + l];
                float w00 = wl * (1.f - wx) * (1.f - wy) * (float)(xi0 && yi0);
                float w10 = wl * wx * (1.f - wy)         * (float)(xi1 && yi0);
                float w01 = wl * (1.f - wx) * wy         * (float)(xi0 && yi1);
                float w11 = wl * wx * wy                 * (float)(xi1 && yi1);
                int x0c = min(max(x0, 0), Wl - 1), x1c = min(max(x0 + 1, 0), Wl - 1);
                int y0c = min(max(y0, 0), Hl - 1), y1c = min(max(y0 + 1, 0), Hl - 1);
                int base = loff[l] + n * Hl * Wl * 128;
                int idx = atomicAdd(&cnt[p], 1);
                offs[p][idx][0] = base + (y0c * Wl + x0c) * 128;
                offs[p][idx][1] = base + (y0c * Wl + x1c) * 128;
                offs[p][idx][2] = base + (y1c * Wl + x0c) * 128;
                offs[p][idx][3] = base + (y1c * Wl + x1c) * 128;
                wts[p][idx][0] = w00; wts[p][idx][1] = w10;
                wts[p][idx][2] = w01; wts[p][idx][3] = w11;
            }
        }
    }
    __syncthreads();

    #pragma unroll 1
    for (int i = 0; i < 4; i++) {
        int p = wv * 4 + i;
        int np = cnt[p];
        floatx2 a = acc[i];
        #pragma unroll 1
        for (int j = 0; j < np; j++) {
            int4   o = *(const int4*)&offs[p][j][0];
            float4 w = *(const float4*)&wts[p][j][0];
            unsigned int v0 = ((const unsigned int*)(featT + o.x))[lane];
            unsigned int v1 = ((const unsigned int*)(featT + o.y))[lane];
            unsigned int v2 = ((const unsigned int*)(featT + o.z))[lane];
            unsigned int v3 = ((const unsigned int*)(featT + o.w))[lane];
            a += bf2x(v0) * w.x;
            a += bf2x(v1) * w.y;
            a += bf2x(v2) * w.z;
            a += bf2x(v3) * w.w;
        }
        acc[i] = a;
    }
    #pragma unroll
    for (int i = 0; i < 4; i++) {
        union { __hip_bfloat16 h[2]; unsigned int u; } pk;
        pk.h[0] = __float2bfloat16(acc[i].x);
        pk.h[1] = __float2bfloat16(acc[i].y);
        *(unsigned int*)&sf[(size_t)pix * 1024 + (wv * 4 + i) * 128 + 2 * lane] = pk.u;
    }
}

extern "C" void kernel_launch(void* const* d_in, const int* in_sizes, int n_in,
                              void* d_out, int out_size, void* d_ws, size_t ws_size,
                              hipStream_t stream)
{
    const float* feat[4] = {(const float*)d_in[0], (const float*)d_in[1],
                            (const float*)d_in[2], (const float*)d_in[3]};
    const float* l2i       = (const float*)d_in[4];
    const float* bev_query = (const float*)d_in[5];
    const float* bev_pos   = (const float*)d_in[6];
    const float* in_w  = (const float*)d_in[7];  const float* in_b  = (const float*)d_in[8];
    const float* off_w = (const float*)d_in[9];  const float* off_b = (const float*)d_in[10];
    const float* sw_w  = (const float*)d_in[11]; const float* sw_b  = (const float*)d_in[12];
    const float* pe_w1 = (const float*)d_in[13]; const float* pe_b1 = (const float*)d_in[14];
    const float* pe_w2 = (const float*)d_in[15]; const float* pe_b2 = (const float*)d_in[16];
    const float* mid_w1 = (const float*)d_in[17]; const float* mid_b1 = (const float*)d_in[18];
    const float* mid_w2 = (const float*)d_in[19]; const float* mid_b2 = (const float*)d_in[20];
    const float* mid_w3 = (const float*)d_in[21]; const float* mid_b3 = (const float*)d_in[22];
    const float* out_w  = (const float*)d_in[23]; const float* out_b  = (const float*)d_in[24];

    float* ws = (float*)d_ws;
    // workspace layout (floats), total ~27,028,480 fl = 108.1 MB
    float* fTf = ws;                    // 1,436,160 : transposed feats bf16 (2,872,320 elems)
    __hip_bfloat16* fT = (__hip_bfloat16*)fTf;
    float* Bb  = fTf + 1436160;         // 2,097,152 : conv out / offsw raw / m3 (CHW)
    float* Cb  = Bb + 2097152;          // 2,097,152 : q0 / conv2 out
    float* Gb  = Cb + 2097152;          // 2,097,152 : q1 (CHW)
    float* Dp  = Gb + 2097152;          //   393,216 : pts
    float* Eb  = Dp + 393216;           //   524,288 : swn
    float* QTf = Eb + 524288;           // 1,081,600 : padded HWC bf16 (130*130*128), serial reuse
    __hip_bfloat16* qT = (__hip_bfloat16*)QTf;
    float* SFf = QTf + 1081600;         // 8,388,608 : sf bf16 131072x128
    __hip_bfloat16* sfb = (__hip_bfloat16*)SFf;
    float* M1f = SFf + 8388608;         // 4,194,304 : m1 bf16 | (with M2f) chunked PE hidden
    __hip_bfloat16* m1b = (__hip_bfloat16*)M1f;
    __hip_bfloat16* hb  = (__hip_bfloat16*)M1f;     // 65536 x 256 bf16 (M1f+M2f)
    float* M2f = M1f + 4194304;         // 4,194,304 : m2 bf16
    __hip_bfloat16* m2b = (__hip_bfloat16*)M2f;
    float* Wc  = M2f + 4194304;         //    73,728 : conv weights bf16
    __hip_bfloat16* Wcv = (__hip_bfloat16*)Wc;
    float* W1f = Wc + 73728;            //   262,144
    __hip_bfloat16* Wb1 = (__hip_bfloat16*)W1f;
    float* W2f = W1f + 262144;          //   131,072
    __hip_bfloat16* Wb2 = (__hip_bfloat16*)W2f;
    float* W3f = W2f + 131072;          //    32,768
    __hip_bfloat16* Wb3 = (__hip_bfloat16*)W3f;
    float* WPf = W3f + 32768;           //    16,384 : pe_w2^T bf16
    __hip_bfloat16* Wpe = (__hip_bfloat16*)WPf;
    float* WOf = WPf + 16384;           //     8,192 : offsw packed weight bf16 [128][128]
    __hip_bfloat16* Wof = (__hip_bfloat16*)WOf;
    float* Bof = WOf + 8192;            //       128 : offsw packed bias fp32

    float* q_out = (float*)d_out;
    float* h_out = q_out + 2097152;

    // zero padded HWC buffer border once (interior overwritten by each fill)
    hipMemsetAsync(qT, 0, (size_t)130 * 130 * 128 * sizeof(__hip_bfloat16), stream);

    const int lH[4] = {32, 16, 8, 4}, lW[4] = {88, 44, 22, 11};
    const int loff[4] = {0, 2162688, 2703360, 2838528};
    for (int l = 0; l < 4; l++) {
        int total = 6 * lH[l] * lW[l] * 128;
        feat_transpose_k<<<(total + 255) / 256, 256, 0, stream>>>(feat[l], fT + loff[l], lH[l], lW[l], total);
    }
    // weight prep
    cvt_bf16_k<<<(524288 + 255) / 256, 256, 0, stream>>>(mid_w1, Wb1, 524288);
    cvt_bf16_k<<<(262144 + 255) / 256, 256, 0, stream>>>(mid_w2, Wb2, 262144);
    cvt_bf16_k<<<(65536  + 255) / 256, 256, 0, stream>>>(mid_w3, Wb3, 65536);
    cvt_pew2T_k<<<128, 256, 0, stream>>>(pe_w2, Wpe);
    offsw_prep_k<<<128, 128, 0, stream>>>(off_w, off_b, sw_w, sw_b, Wof, Bof);

    // conv1: q0 = inorm(bev_query + conv3x3(bev_query))
    convw_k<<<128, 256, 0, stream>>>(in_w, Wcv);
    chw2hwc_pad_k<<<256, 256, 0, stream>>>(bev_query, qT);
    bgemm_k<64, 0, 1, 1><<<dim3(1, 256), 256, 0, stream>>>(qT, Wcv, in_b, Bb, HW, 1152, 128);
    inorm_k<<<128, 256, 0, stream>>>(Bb, bev_query, Cb);

    // offsets/sample-weights as MFMA GEMM over center tap of padded q0 (Bb is dead -> raw out)
    chw2hwc_pad_k<<<256, 256, 0, stream>>>(Cb, qT);
    bgemm_k<64, 0, 1, 1><<<dim3(1, 256), 256, 0, stream>>>(qT + 131 * 128, Wof, Bof, Bb, HW, 128, 128);
    offpost_k<<<64, 256, 0, stream>>>(Bb, bev_pos, Dp, Eb, h_out);

    // PE: hidden (bf16) then MFMA GEMM into sf, in 2 row-chunks of 65536
    for (int ch = 0; ch < 2; ch++) {
        size_t row0 = (size_t)ch * 65536;
        pe_hidden_k<<<8192, 256, 0, stream>>>(Dp + row0 * 3, pe_w1, pe_b1, hb);
        bgemm_k<128, 0, 0, 0><<<dim3(1, 512), 256, 0, stream>>>(
            hb, Wpe, pe_b2, sfb + row0 * 128, 65536, 256, 128);
    }

    // sampling accumulates taps onto sf
    sample_k<<<HW, 128, 0, stream>>>(fT, Dp, Eb, l2i, sfb);

    // mid MLP (bf16 MFMA): 1024 -> 512 gelu -> 512 gelu -> 128 linear (CHW fp32)
    bgemm_k<128, 1, 0, 0><<<dim3(4, 128), 256, 0, stream>>>(sfb, Wb1, mid_b1, m1b, HW, 1024, 512);
    bgemm_k<128, 1, 0, 0><<<dim3(4, 128), 256, 0, stream>>>(m1b, Wb2, mid_b2, m2b, HW, 512, 512);
    bgemm_k<64, 0, 1, 0><<<dim3(1, 256), 256, 0, stream>>>(m2b, Wb3, mid_b3, Bb, HW, 512, 128);

    // q1 = inorm(q0 + m)
    inorm_k<<<128, 256, 0, stream>>>(Cb, Bb, Gb);

    // conv2: q = inorm(q1 + conv3x3(q1))
    convw_k<<<128, 256, 0, stream>>>(out_w, Wcv);
    chw2hwc_pad_k<<<256, 256, 0, stream>>>(Gb, qT);
    bgemm_k<64, 0, 1, 1><<<dim3(1, 256), 256, 0, stream>>>(qT, Wcv, out_b, Cb, HW, 1152, 128);
    inorm_k<<<128, 256, 0, stream>>>(Cb, Gb, q_out);
}

// Round 8
// 454.129 us; speedup vs baseline: 4.6341x; 1.1409x over previous
//
#include <hip/hip_runtime.h>
#include <hip/hip_bf16.h>
#include <math.h>

#define HW 16384   // 128*128 bev pixels

typedef __attribute__((ext_vector_type(8))) short short8;
typedef __attribute__((ext_vector_type(4))) float floatx4;
typedef __attribute__((ext_vector_type(2))) float floatx2;

__device__ __forceinline__ float gelu_exact(float x){
    return 0.5f * x * (1.0f + erff(x * 0.7071067811865475f));
}

__device__ __forceinline__ floatx2 bf2x(unsigned int u){
    floatx2 r;
    r.x = __uint_as_float(u << 16);
    r.y = __uint_as_float(u & 0xffff0000u);
    return r;
}

// ---------------- all-level feat transpose: (N,C,H,W) fp32 -> (N,H,W,C) bf16 ----------------
__global__ __launch_bounds__(256) void feat_transpose_all_k(
    const float* __restrict__ f0, const float* __restrict__ f1,
    const float* __restrict__ f2, const float* __restrict__ f3,
    __hip_bfloat16* __restrict__ out)
{
    int idx = blockIdx.x * 256 + threadIdx.x;
    const float* in; int Hl, Wl, base;
    if (idx < 2162688)      { in = f0; Hl = 32; Wl = 88; base = 0; }
    else if (idx < 2703360) { in = f1; Hl = 16; Wl = 44; base = 2162688; }
    else if (idx < 2838528) { in = f2; Hl = 8;  Wl = 22; base = 2703360; }
    else                    { in = f3; Hl = 4;  Wl = 11; base = 2838528; }
    int r   = idx - base;
    int c   = r & 127;
    int pix = r >> 7;
    int x   = pix % Wl;
    int tt  = pix / Wl;
    int y   = tt % Hl;
    int n   = tt / Hl;
    out[idx] = __float2bfloat16(in[((n * 128 + c) * Hl + y) * Wl + x]);
}

// ---------------- unified weight prep (block-range dispatch) ----------------
// [0,2048) mid_w1 | [2048,3072) mid_w2 | [3072,3328) mid_w3 | [3328,3456) pe_w2^T
// [3456,3584) offsw pack | [3584,3712) conv1 w | [3712,3840) conv2 w
__global__ __launch_bounds__(256) void prep_k(
    const float* __restrict__ mid_w1, const float* __restrict__ mid_w2,
    const float* __restrict__ mid_w3, const float* __restrict__ pe_w2,
    const float* __restrict__ off_w,  const float* __restrict__ off_b,
    const float* __restrict__ sw_w,   const float* __restrict__ sw_b,
    const float* __restrict__ in_w,   const float* __restrict__ out_w,
    __hip_bfloat16* __restrict__ Wb1, __hip_bfloat16* __restrict__ Wb2,
    __hip_bfloat16* __restrict__ Wb3, __hip_bfloat16* __restrict__ Wpe,
    __hip_bfloat16* __restrict__ Wof, float* __restrict__ Bof,
    __hip_bfloat16* __restrict__ Wcv1, __hip_bfloat16* __restrict__ Wcv2)
{
    int b = blockIdx.x, t = threadIdx.x;
    if (b < 2048) {
        int i = b * 256 + t; Wb1[i] = __float2bfloat16(mid_w1[i]);
    } else if (b < 3072) {
        int i = (b - 2048) * 256 + t; Wb2[i] = __float2bfloat16(mid_w2[i]);
    } else if (b < 3328) {
        int i = (b - 3072) * 256 + t; Wb3[i] = __float2bfloat16(mid_w3[i]);
    } else if (b < 3456) {
        int n = b - 3328; Wpe[n * 256 + t] = __float2bfloat16(pe_w2[t * 128 + n]);
    } else if (b < 3584) {
        int n = b - 3456;
        if (t < 128) {
            float w = 0.f;
            if (n < 24)      w = off_w[n * 128 + t];
            else if (n < 56) w = sw_w[(n - 24) * 128 + t];
            Wof[n * 128 + t] = __float2bfloat16(w);
            if (t == 0) Bof[n] = (n < 24) ? off_b[n] : ((n < 56) ? sw_b[n - 24] : 0.f);
        }
    } else if (b < 3712) {
        int o = b - 3584;
        for (int idx = t; idx < 1152; idx += 256) {
            int s = idx >> 7, i = idx & 127;
            Wcv1[o * 1152 + idx] = __float2bfloat16(in_w[(o * 128 + i) * 9 + s]);
        }
    } else {
        int o = b - 3712;
        for (int idx = t; idx < 1152; idx += 256) {
            int s = idx >> 7, i = idx & 127;
            Wcv2[o * 1152 + idx] = __float2bfloat16(out_w[(o * 128 + i) * 9 + s]);
        }
    }
}

// ---------------- CHW fp32 [128][128^2] -> padded HWC bf16 [130][130][128] (interior) ----------------
__global__ __launch_bounds__(256) void chw2hwc_pad_k(
    const float* __restrict__ q, __hip_bfloat16* __restrict__ out)
{
    __shared__ float tile[128][65];
    int b = blockIdx.x;            // 256 blocks: y = b>>1, x0 = (b&1)*64
    int y = b >> 1, x0 = (b & 1) * 64;
    int t = threadIdx.x;
    int xi = t & 63, c0 = t >> 6;
    for (int c = c0; c < 128; c += 4)
        tile[c][xi] = q[c * HW + y * 128 + x0 + xi];
    __syncthreads();
    int xp = t >> 2, cg = (t & 3) * 32;
    __hip_bfloat16* dst = out + ((size_t)(y + 1) * 130 + (x0 + 1 + xp)) * 128;
    #pragma unroll
    for (int g = 0; g < 4; g++) {
        int c = cg + g * 8;
        union { __hip_bfloat16 h[8]; uint4 u; } pk;
        #pragma unroll
        for (int j = 0; j < 8; j++) pk.h[j] = __float2bfloat16(tile[c + j][xp]);
        *(uint4*)&dst[c] = pk.u;
    }
}

// ---------------- bf16 MFMA GEMM: out[m][n] = act(bias[n] + sum_k X[m][k] W[n][k]) ----------------
// BN = 128 fixed. OUTT: 0 -> bf16 [M][N]; 1 -> fp32 [N][M] (CHW, + optional residual res[n][m]).
// CONV: X is padded HWC bf16 [130][130][128]; k = s*128+c.
template<int BM, int ACT, int OUTT, int CONV>
__global__ __launch_bounds__(256) void bgemm_k(
    const __hip_bfloat16* __restrict__ X, const __hip_bfloat16* __restrict__ W,
    const float* __restrict__ bias, void* __restrict__ outp,
    const float* __restrict__ res,
    int M, int K, int N)
{
    constexpr int ROWS = BM + 128;
    __shared__ __align__(16) __hip_bfloat16 SH[ROWS * 32];
    __hip_bfloat16* As = SH;
    __hip_bfloat16* Bs = SH + BM * 32;
    int t = threadIdx.x;
    int w = t >> 6, lane = t & 63;
    int mb = blockIdx.y * BM, nb = blockIdx.x * 128;
    int cy = mb >> 7, cx = mb & 127;   // conv tile coords (CONV only)
    constexpr int WM = BM / 2;
    constexpr int MI = WM / 16;
    int wm = (w & 1) * WM, wn = (w >> 1) * 64;
    int lm = lane & 15, lq = lane >> 4;
    floatx4 zero = {0.f, 0.f, 0.f, 0.f};
    floatx4 acc[MI][4];
    #pragma unroll
    for (int i = 0; i < MI; i++)
        #pragma unroll
        for (int j = 0; j < 4; j++) acc[i][j] = zero;
    constexpr int ITERS = (ROWS * 4) / 256;
    for (int kb = 0; kb < K; kb += 32) {
        int s = kb >> 7;
        int dyi = s / 3, dxi = s - dyi * 3;   // tap indices (CONV only)
        __syncthreads();
        #pragma unroll
        for (int it = 0; it < ITERS; it++) {
            int chunk = it * 256 + t;
            int row = chunk >> 2, ko = (chunk & 3) * 8;
            const __hip_bfloat16* src;
            if (row < BM) {
                if (CONV)
                    src = X + (((size_t)(cy + dyi) * 130) + (cx + dxi + row)) * 128 + (kb & 127) + ko;
                else
                    src = X + (size_t)(mb + row) * K + kb + ko;
            } else {
                src = W + (size_t)(nb + row - BM) * K + kb + ko;
            }
            __builtin_amdgcn_global_load_lds(
                (const __attribute__((address_space(1))) void*)src,
                (__attribute__((address_space(3))) void*)&SH[(size_t)(it * 256 + (t & ~63)) * 8],
                16, 0, 0);
        }
        __syncthreads();
        short8 af[MI], bf[4];
        #pragma unroll
        for (int i = 0; i < MI; i++)
            af[i] = *(const short8*)&As[(wm + i * 16 + lm) * 32 + lq * 8];
        #pragma unroll
        for (int j = 0; j < 4; j++)
            bf[j] = *(const short8*)&Bs[(wn + j * 16 + lm) * 32 + lq * 8];
        #pragma unroll
        for (int i = 0; i < MI; i++)
            #pragma unroll
            for (int j = 0; j < 4; j++)
                acc[i][j] = __builtin_amdgcn_mfma_f32_16x16x32_bf16(af[i], bf[j], acc[i][j], 0, 0, 0);
    }
    #pragma unroll
    for (int i = 0; i < MI; i++) {
        #pragma unroll
        for (int j = 0; j < 4; j++) {
            int n = nb + wn + j * 16 + lm;
            float bv = bias[n];
            #pragma unroll
            for (int r = 0; r < 4; r++) {
                int m = mb + wm + i * 16 + lq * 4 + r;
                float v = acc[i][j][r] + bv;
                if (ACT) v = gelu_exact(v);
                if (OUTT == 0) {
                    ((__hip_bfloat16*)outp)[(size_t)m * N + n] = __float2bfloat16(v);
                } else {
                    if (res) v += res[(size_t)n * M + m];
                    ((float*)outp)[(size_t)n * M + m] = v;
                }
            }
        }
    }
}

// ---------------- fused PE: hidden = relu(rn @ w1 + b1) computed on the fly, GEMM vs Wpe ----------------
// out[row][128] bf16, row = pix*8+p.  Grid: M/128 blocks, 256 threads.
__global__ __launch_bounds__(256) void pe_bgemm_k(
    const float* __restrict__ pts, const float* __restrict__ pe_w1,
    const float* __restrict__ pe_b1, const __hip_bfloat16* __restrict__ W,
    const float* __restrict__ bias, __hip_bfloat16* __restrict__ out)
{
    __shared__ __align__(16) __hip_bfloat16 As[128 * 32];
    __shared__ __align__(16) __hip_bfloat16 Bs[128 * 32];
    __shared__ __align__(16) float wps[4][256];   // [b1, w1_x, w1_y, w1_z][256]
    int t = threadIdx.x;
    int w = t >> 6, lane = t & 63;
    int mb = blockIdx.x * 128;
    {   // stage w1/b1: 4 dims x 64 threads x float4
        int d = t >> 6, c = (t & 63) * 4;
        float4 v;
        if (d == 0) v = *(const float4*)&pe_b1[c];
        else        v = *(const float4*)&pe_w1[(d - 1) * 256 + c];
        *(float4*)&wps[d][c] = v;
    }
    int cg = t & 3;            // col-group within k-tile: cols kb+cg*8 .. +7
    int r0 = t >> 2;           // rows r0 and r0+64
    float rn[2][3];
    #pragma unroll
    for (int h = 0; h < 2; h++) {
        int r = mb + r0 + h * 64;
        rn[h][0] = (pts[(size_t)r * 3 + 0] + 50.f) * 0.01f;
        rn[h][1] = (pts[(size_t)r * 3 + 1] + 50.f) * 0.01f;
        rn[h][2] = (pts[(size_t)r * 3 + 2] + 4.f) * 0.125f;
    }
    int wm = (w & 1) * 64, wn = (w >> 1) * 64;
    int lm = lane & 15, lq = lane >> 4;
    floatx4 zero = {0.f, 0.f, 0.f, 0.f};
    floatx4 acc[4][4];
    #pragma unroll
    for (int i = 0; i < 4; i++)
        #pragma unroll
        for (int j = 0; j < 4; j++) acc[i][j] = zero;
    for (int kb = 0; kb < 256; kb += 32) {
        __syncthreads();
        // stage B (Wpe rows, K=256) async
        #pragma unroll
        for (int it = 0; it < 2; it++) {
            int chunk = it * 256 + t;
            int brow = chunk >> 2, ko = (chunk & 3) * 8;
            const __hip_bfloat16* src = W + (size_t)brow * 256 + kb + ko;
            __builtin_amdgcn_global_load_lds(
                (const __attribute__((address_space(1))) void*)src,
                (__attribute__((address_space(3))) void*)&Bs[(size_t)(it * 256 + (t & ~63)) * 8],
                16, 0, 0);
        }
        // compute A-tile: rows r0, r0+64, cols kb+cg*8 .. +7
        int c0 = kb + cg * 8;
        float4 bva = *(const float4*)&wps[0][c0], bvb = *(const float4*)&wps[0][c0 + 4];
        float4 wxa = *(const float4*)&wps[1][c0], wxb = *(const float4*)&wps[1][c0 + 4];
        float4 wya = *(const float4*)&wps[2][c0], wyb = *(const float4*)&wps[2][c0 + 4];
        float4 wza = *(const float4*)&wps[3][c0], wzb = *(const float4*)&wps[3][c0 + 4];
        #pragma unroll
        for (int h = 0; h < 2; h++) {
            const float* bv = (const float*)&bva;
            const float* wx = (const float*)&wxa;
            const float* wy = (const float*)&wya;
            const float* wz = (const float*)&wza;
            union { __hip_bfloat16 hh[8]; uint4 u; } pk;
            #pragma unroll
            for (int j = 0; j < 4; j++) {
                float v = bv[j] + rn[h][0] * wx[j] + rn[h][1] * wy[j] + rn[h][2] * wz[j];
                pk.hh[j] = __float2bfloat16(fmaxf(v, 0.f));
            }
            bv = (const float*)&bvb; wx = (const float*)&wxb;
            wy = (const float*)&wyb; wz = (const float*)&wzb;
            #pragma unroll
            for (int j = 0; j < 4; j++) {
                float v = bv[j] + rn[h][0] * wx[j] + rn[h][1] * wy[j] + rn[h][2] * wz[j];
                pk.hh[4 + j] = __float2bfloat16(fmaxf(v, 0.f));
            }
            *(uint4*)&As[(r0 + h * 64) * 32 + cg * 8] = pk.u;
        }
        __syncthreads();
        short8 af[4], bf[4];
        #pragma unroll
        for (int i = 0; i < 4; i++)
            af[i] = *(const short8*)&As[(wm + i * 16 + lm) * 32 + lq * 8];
        #pragma unroll
        for (int j = 0; j < 4; j++)
            bf[j] = *(const short8*)&Bs[(wn + j * 16 + lm) * 32 + lq * 8];
        #pragma unroll
        for (int i = 0; i < 4; i++)
            #pragma unroll
            for (int j = 0; j < 4; j++)
                acc[i][j] = __builtin_amdgcn_mfma_f32_16x16x32_bf16(af[i], bf[j], acc[i][j], 0, 0, 0);
    }
    #pragma unroll
    for (int i = 0; i < 4; i++) {
        #pragma unroll
        for (int j = 0; j < 4; j++) {
            int n = wn + j * 16 + lm;
            float bv = bias[n];
            #pragma unroll
            for (int r = 0; r < 4; r++) {
                int m = mb + wm + i * 16 + lq * 4 + r;
                out[(size_t)m * 128 + n] = __float2bfloat16(acc[i][j][r] + bv);
            }
        }
    }
}

// ---------------- instance norm over HW per channel ----------------
__global__ __launch_bounds__(256) void inorm_k(
    const float* __restrict__ a, const float* __restrict__ addc, float* __restrict__ out)
{
    int c = blockIdx.x;
    const float* pa = a + (size_t)c * HW;
    const float* pb = addc ? addc + (size_t)c * HW : nullptr;
    const bool hasb = (pb != nullptr);
    float s = 0.f, s2 = 0.f;
    for (int i = threadIdx.x; i < HW; i += 256) {
        float v = hasb ? (pa[i] + pb[i]) : pa[i];
        s += v; s2 += v * v;
    }
    #pragma unroll
    for (int off = 32; off > 0; off >>= 1) {
        s  += __shfl_down(s,  off);
        s2 += __shfl_down(s2, off);
    }
    __shared__ float ls[4], ls2[4], stats[2];
    int wid = threadIdx.x >> 6, lane = threadIdx.x & 63;
    if (lane == 0) { ls[wid] = s; ls2[wid] = s2; }
    __syncthreads();
    if (threadIdx.x == 0) {
        float t = 0.f, t2 = 0.f;
        for (int i = 0; i < 4; i++) { t += ls[i]; t2 += ls2[i]; }
        float mean = t * (1.0f / HW);
        float var  = t2 * (1.0f / HW) - mean * mean;
        stats[0] = mean;
        stats[1] = rsqrtf(var + 1e-5f);
    }
    __syncthreads();
    float mean = stats[0], rstd = stats[1];
    float* po = out + (size_t)c * HW;
    for (int i = threadIdx.x; i < HW; i += 256) {
        float v = hasb ? (pa[i] + pb[i]) : pa[i];
        po[i] = (v - mean) * rstd;
    }
}

// ---------------- offsw epilogue: raw [n][16384] fp32 -> pts/swn/height ----------------
__global__ __launch_bounds__(256) void offpost_k(
    const float* __restrict__ raw, const float* __restrict__ bev_pos,
    float* __restrict__ pts, float* __restrict__ swn, float* __restrict__ height_out)
{
    int pix = blockIdx.x * 256 + threadIdx.x;
    const float pcmin[3] = {-50.f, -50.f, -4.f};
    const float rng[3]   = {100.f, 100.f, 8.f};
    float bp[3];
    #pragma unroll
    for (int d = 0; d < 3; d++) bp[d] = bev_pos[pix * 3 + d];
    #pragma unroll
    for (int p = 0; p < 8; p++) {
        #pragma unroll
        for (int d = 0; d < 3; d++) {
            float acc = raw[(p * 3 + d) * HW + pix];
            float sv = 1.f / (1.f + expf(-acc));
            float lim = (d == 2) ? (4.0f + 1e-6f) : (0.25f + 1e-6f);
            float offv = sv * 2.f * lim - lim;
            float refv = bp[d] * rng[d] + pcmin[d];
            pts[pix * 24 + p * 3 + d] = refv + offv;
            if (d == 2) height_out[p * HW + pix] = offv;
        }
        float r[4], m = -1e30f;
        #pragma unroll
        for (int l = 0; l < 4; l++) {
            r[l] = raw[(24 + p * 4 + l) * HW + pix];
            m = fmaxf(m, r[l]);
        }
        float sum = 0.f;
        #pragma unroll
        for (int l = 0; l < 4; l++) { r[l] = expf(r[l] - m); sum += r[l]; }
        float inv = 1.f / sum;
        #pragma unroll
        for (int l = 0; l < 4; l++) swn[pix * 32 + p * 4 + l] = r[l] * inv;
    }
}

// ---------------- sampling: phase-1 per-combo projection + cull, phase-2 packed gather ----------------
__global__ __launch_bounds__(128) void sample_k(
    const __hip_bfloat16* __restrict__ featT, const float* __restrict__ pts,
    const float* __restrict__ swn,   const float* __restrict__ l2i,
    __hip_bfloat16* __restrict__ sf)
{
    int pix = blockIdx.x;
    int t = threadIdx.x;
    int lane = t & 63, wv = t >> 6;
    __shared__ float pts_s[24];
    __shared__ float swl_s[32];
    __shared__ float M[96];
    __shared__ __align__(16) int   offs[8][24][4];
    __shared__ __align__(16) float wts[8][24][4];
    __shared__ int cnt[8];
    if (t < 96) M[t] = l2i[t];
    if (t < 24) pts_s[t] = pts[pix * 24 + t];
    if (t < 32) swl_s[t] = swn[pix * 32 + t];
    if (t < 8)  cnt[t] = 0;
    __syncthreads();

    floatx2 acc[4];
    #pragma unroll
    for (int i = 0; i < 4; i++) {
        unsigned int u = *(const unsigned int*)&sf[(size_t)pix * 1024 + (wv * 4 + i) * 128 + 2 * lane];
        acc[i] = bf2x(u);
    }

    const int lHt[4] = {32, 16, 8, 4}, lWt[4] = {88, 44, 22, 11};
    const int loff[4] = {0, 2162688, 2703360, 2838528};
    for (int cb = t; cb < 192; cb += 128) {
        int p = cb / 24;
        int rr = cb - p * 24;
        int n = rr >> 2, l = rr & 3;
        float X = pts_s[p * 3], Y = pts_s[p * 3 + 1], Z = pts_s[p * 3 + 2];
        const float* Mn = &M[n * 16];
        float zc = Mn[8] * X + Mn[9] * Y + Mn[10] * Z + Mn[11];
        if (zc > 1e-5f) {
            float inv = 1.f / zc;
            float xn = (Mn[0] * X + Mn[1] * Y + Mn[2] * Z + Mn[3]) * inv * (1.f / 704.f);
            float yn = (Mn[4] * X + Mn[5] * Y + Mn[6] * Z + Mn[7]) * inv * (1.f / 256.f);
            int Wl = lWt[l], Hl = lHt[l];
            float px = xn * Wl - 0.5f, py = yn * Hl - 0.5f;
            px = fminf(fmaxf(px, -2.f), (float)(Wl + 1));
            py = fminf(fmaxf(py, -2.f), (float)(Hl + 1));
            float x0f = floorf(px), y0f = floorf(py);
            float wx = px - x0f, wy = py - y0f;
            int x0 = (int)x0f, y0 = (int)y0f;
            bool xi0 = (unsigned)x0 < (unsigned)Wl, xi1 = (unsigned)(x0 + 1) < (unsigned)Wl;
            bool yi0 = (unsigned)y0 < (unsigned)Hl, yi1 = (unsigned)(y0 + 1) < (unsigned)Hl;
            if ((xi0 || xi1) && (yi0 || yi1)) {
                float wl = swl_s[p * 4 + l];
                float w00 = wl * (1.f - wx) * (1.f - wy) * (float)(xi0 && yi0);
                float w10 = wl * wx * (1.f - wy)         * (float)(xi1 && yi0);
                float w01 = wl * (1.f - wx) * wy         * (float)(xi0 && yi1);
                float w11 = wl * wx * wy                 * (float)(xi1 && yi1);
                int x0c = min(max(x0, 0), Wl - 1), x1c = min(max(x0 + 1, 0), Wl - 1);
                int y0c = min(max(y0, 0), Hl - 1), y1c = min(max(y0 + 1, 0), Hl - 1);
                int base = loff[l] + n * Hl * Wl * 128;
                int idx = atomicAdd(&cnt[p], 1);
                offs[p][idx][0] = base + (y0c * Wl + x0c) * 128;
                offs[p][idx][1] = base + (y0c * Wl + x1c) * 128;
                offs[p][idx][2] = base + (y1c * Wl + x0c) * 128;
                offs[p][idx][3] = base + (y1c * Wl + x1c) * 128;
                wts[p][idx][0] = w00; wts[p][idx][1] = w10;
                wts[p][idx][2] = w01; wts[p][idx][3] = w11;
            }
        }
    }
    __syncthreads();

    #pragma unroll 1
    for (int i = 0; i < 4; i++) {
        int p = wv * 4 + i;
        int np = cnt[p];
        floatx2 a = acc[i];
        #pragma unroll 1
        for (int j = 0; j < np; j++) {
            int4   o = *(const int4*)&offs[p][j][0];
            float4 w = *(const float4*)&wts[p][j][0];
            unsigned int v0 = ((const unsigned int*)(featT + o.x))[lane];
            unsigned int v1 = ((const unsigned int*)(featT + o.y))[lane];
            unsigned int v2 = ((const unsigned int*)(featT + o.z))[lane];
            unsigned int v3 = ((const unsigned int*)(featT + o.w))[lane];
            a += bf2x(v0) * w.x;
            a += bf2x(v1) * w.y;
            a += bf2x(v2) * w.z;
            a += bf2x(v3) * w.w;
        }
        acc[i] = a;
    }
    #pragma unroll
    for (int i = 0; i < 4; i++) {
        union { __hip_bfloat16 h[2]; unsigned int u; } pk;
        pk.h[0] = __float2bfloat16(acc[i].x);
        pk.h[1] = __float2bfloat16(acc[i].y);
        *(unsigned int*)&sf[(size_t)pix * 1024 + (wv * 4 + i) * 128 + 2 * lane] = pk.u;
    }
}

extern "C" void kernel_launch(void* const* d_in, const int* in_sizes, int n_in,
                              void* d_out, int out_size, void* d_ws, size_t ws_size,
                              hipStream_t stream)
{
    const float* feat[4] = {(const float*)d_in[0], (const float*)d_in[1],
                            (const float*)d_in[2], (const float*)d_in[3]};
    const float* l2i       = (const float*)d_in[4];
    const float* bev_query = (const float*)d_in[5];
    const float* bev_pos   = (const float*)d_in[6];
    const float* in_w  = (const float*)d_in[7];  const float* in_b  = (const float*)d_in[8];
    const float* off_w = (const float*)d_in[9];  const float* off_b = (const float*)d_in[10];
    const float* sw_w  = (const float*)d_in[11]; const float* sw_b  = (const float*)d_in[12];
    const float* pe_w1 = (const float*)d_in[13]; const float* pe_b1 = (const float*)d_in[14];
    const float* pe_w2 = (const float*)d_in[15]; const float* pe_b2 = (const float*)d_in[16];
    const float* mid_w1 = (const float*)d_in[17]; const float* mid_b1 = (const float*)d_in[18];
    const float* mid_w2 = (const float*)d_in[19]; const float* mid_b2 = (const float*)d_in[20];
    const float* mid_w3 = (const float*)d_in[21]; const float* mid_b3 = (const float*)d_in[22];
    const float* out_w  = (const float*)d_in[23]; const float* out_b  = (const float*)d_in[24];

    float* ws = (float*)d_ws;
    float* fTf = ws;                    // 1,436,160 : transposed feats bf16
    __hip_bfloat16* fT = (__hip_bfloat16*)fTf;
    float* Bb  = fTf + 1436160;         // 2,097,152 : conv out / offsw raw / m3 (CHW)
    float* Cb  = Bb + 2097152;          // 2,097,152 : q0 / conv2 out
    float* Gb  = Cb + 2097152;          // 2,097,152 : q1 (CHW)
    float* Dp  = Gb + 2097152;          //   393,216 : pts
    float* Eb  = Dp + 393216;           //   524,288 : swn
    float* QTf = Eb + 524288;           // 1,081,600 : padded HWC bf16 (130*130*128)
    __hip_bfloat16* qT = (__hip_bfloat16*)QTf;
    float* SFf = QTf + 1081600;         // 8,388,608 : sf bf16 131072x128
    __hip_bfloat16* sfb = (__hip_bfloat16*)SFf;
    float* M1f = SFf + 8388608;         // 4,194,304 : m1 bf16
    __hip_bfloat16* m1b = (__hip_bfloat16*)M1f;
    float* M2f = M1f + 4194304;         // 4,194,304 : m2 bf16
    __hip_bfloat16* m2b = (__hip_bfloat16*)M2f;
    float* WC1 = M2f + 4194304;         //    73,728 : conv1 weights bf16
    __hip_bfloat16* Wcv1 = (__hip_bfloat16*)WC1;
    float* WC2 = WC1 + 73728;           //    73,728 : conv2 weights bf16
    __hip_bfloat16* Wcv2 = (__hip_bfloat16*)WC2;
    float* W1f = WC2 + 73728;           //   262,144
    __hip_bfloat16* Wb1 = (__hip_bfloat16*)W1f;
    float* W2f = W1f + 262144;          //   131,072
    __hip_bfloat16* Wb2 = (__hip_bfloat16*)W2f;
    float* W3f = W2f + 131072;          //    32,768
    __hip_bfloat16* Wb3 = (__hip_bfloat16*)W3f;
    float* WPf = W3f + 32768;           //    16,384 : pe_w2^T bf16
    __hip_bfloat16* Wpe = (__hip_bfloat16*)WPf;
    float* WOf = WPf + 16384;           //     8,192 : offsw packed weight bf16
    __hip_bfloat16* Wof = (__hip_bfloat16*)WOf;
    float* Bof = WOf + 8192;            //       128 : offsw packed bias fp32

    float* q_out = (float*)d_out;
    float* h_out = q_out + 2097152;

    hipMemsetAsync(qT, 0, (size_t)130 * 130 * 128 * sizeof(__hip_bfloat16), stream);

    feat_transpose_all_k<<<11220, 256, 0, stream>>>(feat[0], feat[1], feat[2], feat[3], fT);
    prep_k<<<3840, 256, 0, stream>>>(mid_w1, mid_w2, mid_w3, pe_w2, off_w, off_b, sw_w, sw_b,
                                     in_w, out_w, Wb1, Wb2, Wb3, Wpe, Wof, Bof, Wcv1, Wcv2);

    // conv1: q0 = inorm(bev_query + conv3x3(bev_query))   [residual fused in epilogue]
    chw2hwc_pad_k<<<256, 256, 0, stream>>>(bev_query, qT);
    bgemm_k<64, 0, 1, 1><<<dim3(1, 256), 256, 0, stream>>>(qT, Wcv1, in_b, Bb, bev_query, HW, 1152, 128);
    inorm_k<<<128, 256, 0, stream>>>(Bb, nullptr, Cb);

    // offsets/sample-weights GEMM over center tap of padded q0 + epilogue
    chw2hwc_pad_k<<<256, 256, 0, stream>>>(Cb, qT);
    bgemm_k<64, 0, 1, 1><<<dim3(1, 256), 256, 0, stream>>>(qT + 131 * 128, Wof, Bof, Bb, nullptr, HW, 128, 128);
    offpost_k<<<64, 256, 0, stream>>>(Bb, bev_pos, Dp, Eb, h_out);

    // fused PE (hidden on the fly + MFMA GEMM) -> sf
    pe_bgemm_k<<<1024, 256, 0, stream>>>(Dp, pe_w1, pe_b1, Wpe, pe_b2, sfb);

    // sampling accumulates taps onto sf
    sample_k<<<HW, 128, 0, stream>>>(fT, Dp, Eb, l2i, sfb);

    // mid MLP: 1024 -> 512 gelu -> 512 gelu -> 128 linear (CHW fp32, +q0 residual)
    bgemm_k<128, 1, 0, 0><<<dim3(4, 128), 256, 0, stream>>>(sfb, Wb1, mid_b1, m1b, nullptr, HW, 1024, 512);
    bgemm_k<128, 1, 0, 0><<<dim3(4, 128), 256, 0, stream>>>(m1b, Wb2, mid_b2, m2b, nullptr, HW, 512, 512);
    bgemm_k<64, 0, 1, 0><<<dim3(1, 256), 256, 0, stream>>>(m2b, Wb3, mid_b3, Bb, Cb, HW, 512, 128);
    inorm_k<<<128, 256, 0, stream>>>(Bb, nullptr, Gb);

    // conv2: q = inorm(q1 + conv3x3(q1))   [residual fused]
    chw2hwc_pad_k<<<256, 256, 0, stream>>>(Gb, qT);
    bgemm_k<64, 0, 1, 1><<<dim3(1, 256), 256, 0, stream>>>(qT, Wcv2, out_b, Cb, Gb, HW, 1152, 128);
    inorm_k<<<128, 256, 0, stream>>>(Cb, nullptr, q_out);
}